// Round 1
// baseline (5814.498 us; speedup 1.0000x reference)
//
#include <hip/hip_runtime.h>
#include <math.h>

#define BS 128
#define NW 80
#define NF 64
#define DD 768
#define INV_TAU 100.0f

// ---------------- K1: sg = sentence_output @ global_mat_weight ----------------
__global__ __launch_bounds__(256) void k_sent_global(
    const float* __restrict__ sent, const float* __restrict__ G, float* __restrict__ sg)
{
    int idx = blockIdx.x * 256 + threadIdx.x;       // 128*768 total
    int t = idx / DD, e = idx % DD;                 // lanes: consecutive e -> coalesced G reads
    const float* srow = sent + t * DD;
    float acc = 0.f;
    #pragma unroll 4
    for (int d = 0; d < DD; ++d) acc += srow[d] * G[d * DD + e];
    sg[idx] = acc;
}

// ---------------- K1b: sim = 0.25 * sg @ traj^T (first writer of sim) ----------------
__global__ __launch_bounds__(256) void k_traj_sent(
    const float* __restrict__ sg, const float* __restrict__ traj, float* __restrict__ sim)
{
    __shared__ float ss[16][33], tt[16][33];
    int tx = threadIdx.x & 15, ty = threadIdx.x >> 4;
    int t0 = blockIdx.y * 16, v0 = blockIdx.x * 16;
    float acc = 0.f;
    for (int kk = 0; kk < DD; kk += 32) {
        for (int l = threadIdx.x; l < 16 * 32; l += 256) {
            int r = l >> 5, c = l & 31;
            ss[r][c] = sg[(t0 + r) * DD + kk + c];
            tt[r][c] = traj[(v0 + r) * DD + kk + c];
        }
        __syncthreads();
        #pragma unroll
        for (int k = 0; k < 32; ++k) acc += ss[ty][k] * tt[tx][k];
        __syncthreads();
    }
    sim[(t0 + ty) * BS + v0 + tx] = 0.25f * acc;
}

// ---------------- K2: wl = word_features(flat) @ local_mat_weight ----------------
// M=10240, N=768, K=768. grid (12, 160), 64x64 tile, 4x4 per thread.
__global__ __launch_bounds__(256) void k_wl(
    const float* __restrict__ wf, const float* __restrict__ L, float* __restrict__ wl)
{
    __shared__ float As[64][17];  // [m][k]
    __shared__ float Bs[16][65];  // [k][e]
    int tx = threadIdx.x & 15, ty = threadIdx.x >> 4;
    int m0 = blockIdx.y * 64, e0 = blockIdx.x * 64;
    float acc[4][4] = {};
    for (int kk = 0; kk < DD; kk += 16) {
        for (int l = threadIdx.x; l < 64 * 16; l += 256) {
            int m = l >> 4, k = l & 15;
            As[m][k] = wf[(m0 + m) * DD + kk + k];
        }
        for (int l = threadIdx.x; l < 16 * 64; l += 256) {
            int k = l >> 6, e = l & 63;
            Bs[k][e] = L[(kk + k) * DD + e0 + e];
        }
        __syncthreads();
        #pragma unroll
        for (int k = 0; k < 16; ++k) {
            float a[4], b[4];
            #pragma unroll
            for (int i = 0; i < 4; ++i) a[i] = As[ty + 16 * i][k];
            #pragma unroll
            for (int j = 0; j < 4; ++j) b[j] = Bs[k][tx + 16 * j];
            #pragma unroll
            for (int i = 0; i < 4; ++i)
                #pragma unroll
                for (int j = 0; j < 4; ++j) acc[i][j] += a[i] * b[j];
        }
        __syncthreads();
    }
    #pragma unroll
    for (int i = 0; i < 4; ++i)
        #pragma unroll
        for (int j = 0; j < 4; ++j)
            wl[(m0 + ty + 16 * i) * DD + e0 + tx + 16 * j] = acc[i][j];
}

// ---------------- K3: video_word — fused A-GEMM + col-softmax + bilinear ----------------
// grid (2, 128): (v-half, t). A[w][v'] = wf[t,w]·traj[v0+v'],  M=80,N=64,K=768
__global__ __launch_bounds__(256, 2) void k_video_word(
    const float* __restrict__ wf, const float* __restrict__ traj,
    const float* __restrict__ Wl, float* __restrict__ sim)
{
    __shared__ __align__(16) float As[NW][36];
    __shared__ __align__(16) float Bs[64][36];
    __shared__ float Am[NW][65];
    __shared__ float Pm[NW][65];
    int tx = threadIdx.x & 15, ty = threadIdx.x >> 4;
    int t = blockIdx.y, v0 = blockIdx.x * 64;
    const float* wft = wf + t * NW * DD;
    float acc[5][4] = {};
    for (int kk = 0; kk < DD; kk += 32) {
        for (int l = threadIdx.x; l < NW * 32; l += 256) {
            int w = l >> 5, k = l & 31;
            As[w][k] = wft[w * DD + kk + k];
        }
        for (int l = threadIdx.x; l < 64 * 32; l += 256) {
            int v = l >> 5, k = l & 31;
            Bs[v][k] = traj[(v0 + v) * DD + kk + k];
        }
        __syncthreads();
        #pragma unroll
        for (int k = 0; k < 32; k += 4) {
            float4 a[5], b[4];
            #pragma unroll
            for (int i = 0; i < 5; ++i) a[i] = *(const float4*)&As[tx + 16 * i][k];
            #pragma unroll
            for (int j = 0; j < 4; ++j) b[j] = *(const float4*)&Bs[ty + 16 * j][k];
            #pragma unroll
            for (int i = 0; i < 5; ++i)
                #pragma unroll
                for (int j = 0; j < 4; ++j)
                    acc[i][j] += a[i].x * b[j].x + a[i].y * b[j].y + a[i].z * b[j].z + a[i].w * b[j].w;
        }
        __syncthreads();
    }
    #pragma unroll
    for (int i = 0; i < 5; ++i)
        #pragma unroll
        for (int j = 0; j < 4; ++j) Am[tx + 16 * i][ty + 16 * j] = acc[i][j];
    __syncthreads();
    if (threadIdx.x < 64) {                 // softmax over w per column v'
        int v = threadIdx.x;
        float m = -1e30f;
        for (int w = 0; w < NW; ++w) m = fmaxf(m, Am[w][v]);
        float s = 0.f;
        for (int w = 0; w < NW; ++w) { float e = __expf((Am[w][v] - m) * INV_TAU); Pm[w][v] = e; s += e; }
        float r = 1.f / s;
        for (int w = 0; w < NW; ++w) Pm[w][v] *= r;
    }
    __syncthreads();
    // m[u][v'] = sum_w Wl[w][u]*Pm[w][v'];  u = tx+16i, v' = ty+16j
    float mm[5][4] = {};
    for (int w = 0; w < NW; ++w) {
        float a[5], b[4];
        #pragma unroll
        for (int i = 0; i < 5; ++i) a[i] = Wl[w * NW + tx + 16 * i];
        #pragma unroll
        for (int j = 0; j < 4; ++j) b[j] = Pm[w][ty + 16 * j];
        #pragma unroll
        for (int i = 0; i < 5; ++i)
            #pragma unroll
            for (int j = 0; j < 4; ++j) mm[i][j] += a[i] * b[j];
    }
    #pragma unroll
    for (int j = 0; j < 4; ++j) {           // vw[v'] = sum_u m*A, reduce over tx
        float p = 0.f;
        #pragma unroll
        for (int i = 0; i < 5; ++i) p += mm[i][j] * Am[tx + 16 * i][ty + 16 * j];
        for (int o = 8; o; o >>= 1) p += __shfl_xor(p, o, 16);
        if (tx == 0) sim[t * BS + v0 + ty + 16 * j] += 0.25f * p;
    }
}

// ---------------- K4: sentence_frame — fused B-GEMM + row-softmax + bilinear ----------------
// grid (2, 128): (t-half, v). B[t'][f] = sent[t0+t']·ff[v,f], M=64,N=64,K=768
__global__ __launch_bounds__(256, 2) void k_sent_frame(
    const float* __restrict__ sent, const float* __restrict__ ff,
    const float* __restrict__ Fl, float* __restrict__ sim)
{
    __shared__ __align__(16) float Ss[64][36];
    __shared__ __align__(16) float Fs[64][36];
    __shared__ float Bm[64][65];
    __shared__ float Pm[64][65];
    int tx = threadIdx.x & 15, ty = threadIdx.x >> 4;
    int v = blockIdx.y, t0 = blockIdx.x * 64;
    const float* ffv = ff + v * NF * DD;
    float acc[4][4] = {};
    for (int kk = 0; kk < DD; kk += 32) {
        for (int l = threadIdx.x; l < 64 * 32; l += 256) {
            int r = l >> 5, k = l & 31;
            Ss[r][k] = sent[(t0 + r) * DD + kk + k];
            Fs[r][k] = ffv[r * DD + kk + k];
        }
        __syncthreads();
        #pragma unroll
        for (int k = 0; k < 32; k += 4) {
            float4 a[4], b[4];
            #pragma unroll
            for (int i = 0; i < 4; ++i) a[i] = *(const float4*)&Ss[tx + 16 * i][k];
            #pragma unroll
            for (int j = 0; j < 4; ++j) b[j] = *(const float4*)&Fs[ty + 16 * j][k];
            #pragma unroll
            for (int i = 0; i < 4; ++i)
                #pragma unroll
                for (int j = 0; j < 4; ++j)
                    acc[i][j] += a[i].x * b[j].x + a[i].y * b[j].y + a[i].z * b[j].z + a[i].w * b[j].w;
        }
        __syncthreads();
    }
    #pragma unroll
    for (int i = 0; i < 4; ++i)
        #pragma unroll
        for (int j = 0; j < 4; ++j) Bm[tx + 16 * i][ty + 16 * j] = acc[i][j];
    __syncthreads();
    if (threadIdx.x < 64) {                 // softmax over f per row t'
        int r = threadIdx.x;
        float m = -1e30f;
        for (int f = 0; f < NF; ++f) m = fmaxf(m, Bm[r][f]);
        float s = 0.f;
        for (int f = 0; f < NF; ++f) { float e = __expf((Bm[r][f] - m) * INV_TAU); Pm[r][f] = e; s += e; }
        float rr = 1.f / s;
        for (int f = 0; f < NF; ++f) Pm[r][f] *= rr;
    }
    __syncthreads();
    // n[t'][f'] = sum_f Pm[t'][f]*Fl[f][f'];  t' = ty+16i, f' = tx+16j
    float nn[4][4] = {};
    for (int f = 0; f < NF; ++f) {
        float a[4], b[4];
        #pragma unroll
        for (int i = 0; i < 4; ++i) a[i] = Pm[ty + 16 * i][f];
        #pragma unroll
        for (int j = 0; j < 4; ++j) b[j] = Fl[f * NF + tx + 16 * j];
        #pragma unroll
        for (int i = 0; i < 4; ++i)
            #pragma unroll
            for (int j = 0; j < 4; ++j) nn[i][j] += a[i] * b[j];
    }
    #pragma unroll
    for (int i = 0; i < 4; ++i) {           // out[t'] = sum_f' n*B, reduce over tx
        float p = 0.f;
        #pragma unroll
        for (int j = 0; j < 4; ++j) p += nn[i][j] * Bm[ty + 16 * i][tx + 16 * j];
        for (int o = 8; o; o >>= 1) p += __shfl_xor(p, o, 16);
        if (tx == 0) sim[(t0 + ty + 16 * i) * BS + v] += 0.25f * p;
    }
}

// ---------------- K5: frame_word — fully fused per (t,v) ----------------
// grid (128, 128): (v, t). S = wl_t[80,768] @ ff_v[64,768]^T then both softmax paths,
// both mix bilinears, sent2frame + video2word, accumulate 0.125*(s2f+v2w) into sim.
__global__ __launch_bounds__(256, 2) void k_frame_word(
    const float* __restrict__ wl, const float* __restrict__ ff,
    const float* __restrict__ Wm, const float* __restrict__ Fm,
    const float* __restrict__ F2, const float* __restrict__ Wm2,
    float* __restrict__ sim)
{
    __shared__ __align__(16) float As[NW][36];
    __shared__ __align__(16) float Bs[NF][36];
    __shared__ float Sm[NW][65];
    __shared__ float Pm[NW][65];
    __shared__ float wlv[NF], flv[NW], smw[NF], smf[NW];
    __shared__ float s2f_s, v2w_s;
    int tx = threadIdx.x & 15, ty = threadIdx.x >> 4;
    int v = blockIdx.x, t = blockIdx.y;
    const float* wlt = wl + t * NW * DD;
    const float* ffv = ff + v * NF * DD;

    float acc[5][4] = {};
    for (int kk = 0; kk < DD; kk += 32) {
        for (int l = threadIdx.x; l < NW * 32; l += 256) {
            int w = l >> 5, k = l & 31;
            As[w][k] = wlt[w * DD + kk + k];
        }
        for (int l = threadIdx.x; l < NF * 32; l += 256) {
            int f = l >> 5, k = l & 31;
            Bs[f][k] = ffv[f * DD + kk + k];
        }
        __syncthreads();
        #pragma unroll
        for (int k = 0; k < 32; k += 4) {
            float4 a[5], b[4];
            #pragma unroll
            for (int i = 0; i < 5; ++i) a[i] = *(const float4*)&As[tx + 16 * i][k];
            #pragma unroll
            for (int j = 0; j < 4; ++j) b[j] = *(const float4*)&Bs[ty + 16 * j][k];
            #pragma unroll
            for (int i = 0; i < 5; ++i)
                #pragma unroll
                for (int j = 0; j < 4; ++j)
                    acc[i][j] += a[i].x * b[j].x + a[i].y * b[j].y + a[i].z * b[j].z + a[i].w * b[j].w;
        }
        __syncthreads();
    }
    #pragma unroll
    for (int i = 0; i < 5; ++i)             // S[w][f]: w = tx+16i, f = ty+16j
        #pragma unroll
        for (int j = 0; j < 4; ++j) Sm[tx + 16 * i][ty + 16 * j] = acc[i][j];
    __syncthreads();

    // ---- word path: softmax over w per column f ----
    if (threadIdx.x < NF) {
        int f = threadIdx.x;
        float m = -1e30f;
        for (int w = 0; w < NW; ++w) m = fmaxf(m, Sm[w][f]);
        float s = 0.f;
        for (int w = 0; w < NW; ++w) { float e = __expf((Sm[w][f] - m) * INV_TAU); Pm[w][f] = e; s += e; }
        float r = 1.f / s;
        for (int w = 0; w < NW; ++w) Pm[w][f] *= r;
    }
    __syncthreads();
    {   // m[u][f] = sum_w Wm[w][u]*Pm[w][f]; u = tx+16i, f = ty+16j
        float mm[5][4] = {};
        for (int w = 0; w < NW; ++w) {
            float a[5], b[4];
            #pragma unroll
            for (int i = 0; i < 5; ++i) a[i] = Wm[w * NW + tx + 16 * i];
            #pragma unroll
            for (int j = 0; j < 4; ++j) b[j] = Pm[w][ty + 16 * j];
            #pragma unroll
            for (int i = 0; i < 5; ++i)
                #pragma unroll
                for (int j = 0; j < 4; ++j) mm[i][j] += a[i] * b[j];
        }
        #pragma unroll
        for (int j = 0; j < 4; ++j) {       // word_level[f] = sum_u m*S
            float p = 0.f;
            #pragma unroll
            for (int i = 0; i < 5; ++i) p += mm[i][j] * Sm[tx + 16 * i][ty + 16 * j];
            for (int o = 8; o; o >>= 1) p += __shfl_xor(p, o, 16);
            if (tx == 0) wlv[ty + 16 * j] = p;
        }
    }
    __syncthreads();   // all reads of col-Pm done; safe to overwrite

    // ---- frame path: softmax over f per row w ----
    if (threadIdx.x < NW) {
        int w = threadIdx.x;
        float m = -1e30f;
        for (int f = 0; f < NF; ++f) m = fmaxf(m, Sm[w][f]);
        float s = 0.f;
        for (int f = 0; f < NF; ++f) { float e = __expf((Sm[w][f] - m) * INV_TAU); Pm[w][f] = e; s += e; }
        float r = 1.f / s;
        for (int f = 0; f < NF; ++f) Pm[w][f] *= r;
    }
    __syncthreads();
    {   // n[w][f'] = sum_f Pm[w][f]*Fm[f][f']; w = ty+16i (i<5), f' = tx+16j
        float nn[5][4] = {};
        for (int f = 0; f < NF; ++f) {
            float a[5], b[4];
            #pragma unroll
            for (int i = 0; i < 5; ++i) a[i] = Pm[ty + 16 * i][f];
            #pragma unroll
            for (int j = 0; j < 4; ++j) b[j] = Fm[f * NF + tx + 16 * j];
            #pragma unroll
            for (int i = 0; i < 5; ++i)
                #pragma unroll
                for (int j = 0; j < 4; ++j) nn[i][j] += a[i] * b[j];
        }
        #pragma unroll
        for (int i = 0; i < 5; ++i) {       // frame_level[w] = sum_f' n*S
            float p = 0.f;
            #pragma unroll
            for (int j = 0; j < 4; ++j) p += nn[i][j] * Sm[ty + 16 * i][tx + 16 * j];
            for (int o = 8; o; o >>= 1) p += __shfl_xor(p, o, 16);
            if (tx == 0) flv[ty + 16 * i] = p;
        }
    }
    __syncthreads();

    // ---- final softmaxes (two serial threads, different waves) ----
    if (threadIdx.x == 0) {
        float m = -1e30f;
        for (int f = 0; f < NF; ++f) m = fmaxf(m, wlv[f]);
        float s = 0.f;
        for (int f = 0; f < NF; ++f) { float e = __expf((wlv[f] - m) * INV_TAU); smw[f] = e; s += e; }
        float r = 1.f / s;
        for (int f = 0; f < NF; ++f) smw[f] *= r;
    }
    if (threadIdx.x == 64) {
        float m = -1e30f;
        for (int w = 0; w < NW; ++w) m = fmaxf(m, flv[w]);
        float s = 0.f;
        for (int w = 0; w < NW; ++w) { float e = __expf((flv[w] - m) * INV_TAU); smf[w] = e; s += e; }
        float r = 1.f / s;
        for (int w = 0; w < NW; ++w) smf[w] *= r;
    }
    __syncthreads();

    // sent2frame: wave0, lane f' ; bilinear smw^T F2 wlv
    if (threadIdx.x < NF) {
        int fp = threadIdx.x;
        float g = 0.f;
        for (int f = 0; f < NF; ++f) g += smw[f] * F2[f * NF + fp];
        float p = g * wlv[fp];
        for (int o = 32; o; o >>= 1) p += __shfl_xor(p, o, 64);
        if (fp == 0) s2f_s = p;
    }
    // video2word: wave2, lane u (u and u+64 for u<16); bilinear smf^T Wm2 flv
    if (threadIdx.x >= 128 && threadIdx.x < 192) {
        int u = threadIdx.x - 128;
        float g = 0.f;
        for (int w = 0; w < NW; ++w) g += smf[w] * Wm2[w * NW + u];
        float p = g * flv[u];
        if (u < 16) {
            int u2 = u + 64;
            float g2 = 0.f;
            for (int w = 0; w < NW; ++w) g2 += smf[w] * Wm2[w * NW + u2];
            p += g2 * flv[u2];
        }
        for (int o = 32; o; o >>= 1) p += __shfl_xor(p, o, 64);
        if (u == 0) v2w_s = p;
    }
    __syncthreads();
    if (threadIdx.x == 0) sim[t * BS + v] += 0.125f * (s2f_s + v2w_s);
}

// ---------------- K6: loss from sim ----------------
__global__ __launch_bounds__(256) void k_loss(const float* __restrict__ sim, float* __restrict__ out)
{
    __shared__ float S[BS][BS + 1];
    __shared__ float lr[BS], lc[BS];
    for (int l = threadIdx.x; l < BS * BS; l += 256) {
        int r = l >> 7, c = l & 127;
        S[r][c] = sim[l];
    }
    __syncthreads();
    int tid = threadIdx.x;
    if (tid < BS) {
        float m = -1e30f;
        for (int c = 0; c < BS; ++c) m = fmaxf(m, S[tid][c]);
        float s = 0.f;
        for (int c = 0; c < BS; ++c) s += __expf(S[tid][c] - m);
        lr[tid] = m + __logf(s);
    } else {
        int c = tid - BS;
        float m = -1e30f;
        for (int r = 0; r < BS; ++r) m = fmaxf(m, S[r][c]);
        float s = 0.f;
        for (int r = 0; r < BS; ++r) s += __expf(S[r][c] - m);
        lc[c] = m + __logf(s);
    }
    __syncthreads();
    if (tid == 0) {
        float a = 0.f;
        for (int i = 0; i < BS; ++i) a += S[i][i] - 0.5f * lr[i] - 0.5f * lc[i];
        out[0] = -a / (float)BS;
    }
}

extern "C" void kernel_launch(void* const* d_in, const int* in_sizes, int n_in,
                              void* d_out, int out_size, void* d_ws, size_t ws_size,
                              hipStream_t stream)
{
    const float* traj = (const float*)d_in[0];
    const float* ff   = (const float*)d_in[1];
    const float* sent = (const float*)d_in[2];
    const float* wf   = (const float*)d_in[3];
    const float* G    = (const float*)d_in[4];
    const float* Wl   = (const float*)d_in[5];
    const float* Fl   = (const float*)d_in[6];
    const float* L    = (const float*)d_in[7];
    const float* Fm   = (const float*)d_in[8];
    const float* Wm   = (const float*)d_in[9];
    const float* F2   = (const float*)d_in[10];
    const float* Wm2  = (const float*)d_in[11];
    float* out = (float*)d_out;
    float* ws  = (float*)d_ws;

    float* sg  = ws;                         // 128*768
    float* wl  = ws + BS * DD;               // 10240*768
    float* sim = ws + BS * DD + BS * NW * DD;// 128*128

    hipLaunchKernelGGL(k_sent_global, dim3(BS * DD / 256), dim3(256), 0, stream, sent, G, sg);
    hipLaunchKernelGGL(k_traj_sent, dim3(8, 8), dim3(256), 0, stream, sg, traj, sim);
    hipLaunchKernelGGL(k_wl, dim3(12, 160), dim3(256), 0, stream, wf, L, wl);
    hipLaunchKernelGGL(k_video_word, dim3(2, BS), dim3(256), 0, stream, wf, traj, Wl, sim);
    hipLaunchKernelGGL(k_sent_frame, dim3(2, BS), dim3(256), 0, stream, sent, ff, Fl, sim);
    hipLaunchKernelGGL(k_frame_word, dim3(BS, BS), dim3(256), 0, stream, wl, ff, Wm, Fm, F2, Wm2, sim);
    hipLaunchKernelGGL(k_loss, dim3(1), dim3(256), 0, stream, sim, out);
}

// Round 2
// 2026.622 us; speedup vs baseline: 2.8691x; 2.8691x over previous
//
#include <hip/hip_runtime.h>
#include <math.h>

#define BS 128
#define NW 80
#define NF 64
#define DD 768
#define INV_TAU 100.0f

typedef unsigned short u16;
typedef __attribute__((ext_vector_type(8))) short bf16x8;
typedef __attribute__((ext_vector_type(4))) float f32x4;

__device__ __forceinline__ u16 f2bf(float x) {
    unsigned b = __float_as_uint(x);
    return (u16)((b + 0x7fffu + ((b >> 16) & 1u)) >> 16);
}
__device__ __forceinline__ float bf2f(u16 h) { return __uint_as_float(((unsigned)h) << 16); }

__device__ __forceinline__ void gload_lds16(const void* gsrc, void* ldst) {
    __builtin_amdgcn_global_load_lds(
        (const __attribute__((address_space(1))) unsigned int*)gsrc,
        (__attribute__((address_space(3))) unsigned int*)ldst, 16, 0, 0);
}

// ---------------- K1: sg = sentence_output @ global_mat_weight ----------------
__global__ __launch_bounds__(256) void k_sent_global(
    const float* __restrict__ sent, const float* __restrict__ G, float* __restrict__ sg)
{
    int idx = blockIdx.x * 256 + threadIdx.x;
    int t = idx / DD, e = idx % DD;
    const float* srow = sent + t * DD;
    float acc = 0.f;
    #pragma unroll 4
    for (int d = 0; d < DD; ++d) acc += srow[d] * G[d * DD + e];
    sg[idx] = acc;
}

// ---------------- K1b: sim = 0.25 * sg @ traj^T (first writer of sim) ----------------
__global__ __launch_bounds__(256) void k_traj_sent(
    const float* __restrict__ sg, const float* __restrict__ traj, float* __restrict__ sim)
{
    __shared__ float ss[16][33], tt[16][33];
    int tx = threadIdx.x & 15, ty = threadIdx.x >> 4;
    int t0 = blockIdx.y * 16, v0 = blockIdx.x * 16;
    float acc = 0.f;
    for (int kk = 0; kk < DD; kk += 32) {
        for (int l = threadIdx.x; l < 16 * 32; l += 256) {
            int r = l >> 5, c = l & 31;
            ss[r][c] = sg[(t0 + r) * DD + kk + c];
            tt[r][c] = traj[(v0 + r) * DD + kk + c];
        }
        __syncthreads();
        #pragma unroll
        for (int k = 0; k < 32; ++k) acc += ss[ty][k] * tt[tx][k];
        __syncthreads();
    }
    sim[(t0 + ty) * BS + v0 + tx] = 0.25f * acc;
}

// ---------------- K2: wl = wf @ L, output split to bf16 hi/lo ----------------
__global__ __launch_bounds__(256) void k_wl(
    const float* __restrict__ wf, const float* __restrict__ L,
    u16* __restrict__ wl_hi, u16* __restrict__ wl_lo)
{
    __shared__ float As[64][17];
    __shared__ float Bs[16][65];
    int tx = threadIdx.x & 15, ty = threadIdx.x >> 4;
    int m0 = blockIdx.y * 64, e0 = blockIdx.x * 64;
    float acc[4][4] = {};
    for (int kk = 0; kk < DD; kk += 16) {
        for (int l = threadIdx.x; l < 64 * 16; l += 256) {
            int m = l >> 4, k = l & 15;
            As[m][k] = wf[(m0 + m) * DD + kk + k];
        }
        for (int l = threadIdx.x; l < 16 * 64; l += 256) {
            int k = l >> 6, e = l & 63;
            Bs[k][e] = L[(kk + k) * DD + e0 + e];
        }
        __syncthreads();
        #pragma unroll
        for (int k = 0; k < 16; ++k) {
            float a[4], b[4];
            #pragma unroll
            for (int i = 0; i < 4; ++i) a[i] = As[ty + 16 * i][k];
            #pragma unroll
            for (int j = 0; j < 4; ++j) b[j] = Bs[k][tx + 16 * j];
            #pragma unroll
            for (int i = 0; i < 4; ++i)
                #pragma unroll
                for (int j = 0; j < 4; ++j) acc[i][j] += a[i] * b[j];
        }
        __syncthreads();
    }
    #pragma unroll
    for (int i = 0; i < 4; ++i)
        #pragma unroll
        for (int j = 0; j < 4; ++j) {
            float x = acc[i][j];
            size_t idx = (size_t)(m0 + ty + 16 * i) * DD + e0 + tx + 16 * j;
            u16 h = f2bf(x);
            wl_hi[idx] = h;
            wl_lo[idx] = f2bf(x - bf2f(h));
        }
}

// ---------------- K2b: split ff to bf16 hi/lo ----------------
__global__ __launch_bounds__(256) void k_ffsplit(
    const float* __restrict__ x, u16* __restrict__ hi, u16* __restrict__ lo)
{
    int i = blockIdx.x * 256 + threadIdx.x;
    float4 f = *(const float4*)&x[(size_t)i * 4];
    ushort4 h, l;
    h.x = f2bf(f.x); l.x = f2bf(f.x - bf2f(h.x));
    h.y = f2bf(f.y); l.y = f2bf(f.y - bf2f(h.y));
    h.z = f2bf(f.z); l.z = f2bf(f.z - bf2f(h.z));
    h.w = f2bf(f.w); l.w = f2bf(f.w - bf2f(h.w));
    *(ushort4*)&hi[(size_t)i * 4] = h;
    *(ushort4*)&lo[(size_t)i * 4] = l;
}

// ---------------- K3: video_word (unchanged fp32) ----------------
__global__ __launch_bounds__(256, 2) void k_video_word(
    const float* __restrict__ wf, const float* __restrict__ traj,
    const float* __restrict__ Wl, float* __restrict__ sim)
{
    __shared__ __align__(16) float As[NW][36];
    __shared__ __align__(16) float Bs[64][36];
    __shared__ float Am[NW][65];
    __shared__ float Pm[NW][65];
    int tx = threadIdx.x & 15, ty = threadIdx.x >> 4;
    int t = blockIdx.y, v0 = blockIdx.x * 64;
    const float* wft = wf + t * NW * DD;
    float acc[5][4] = {};
    for (int kk = 0; kk < DD; kk += 32) {
        for (int l = threadIdx.x; l < NW * 32; l += 256) {
            int w = l >> 5, k = l & 31;
            As[w][k] = wft[w * DD + kk + k];
        }
        for (int l = threadIdx.x; l < 64 * 32; l += 256) {
            int v = l >> 5, k = l & 31;
            Bs[v][k] = traj[(v0 + v) * DD + kk + k];
        }
        __syncthreads();
        #pragma unroll
        for (int k = 0; k < 32; k += 4) {
            float4 a[5], b[4];
            #pragma unroll
            for (int i = 0; i < 5; ++i) a[i] = *(const float4*)&As[tx + 16 * i][k];
            #pragma unroll
            for (int j = 0; j < 4; ++j) b[j] = *(const float4*)&Bs[ty + 16 * j][k];
            #pragma unroll
            for (int i = 0; i < 5; ++i)
                #pragma unroll
                for (int j = 0; j < 4; ++j)
                    acc[i][j] += a[i].x * b[j].x + a[i].y * b[j].y + a[i].z * b[j].z + a[i].w * b[j].w;
        }
        __syncthreads();
    }
    #pragma unroll
    for (int i = 0; i < 5; ++i)
        #pragma unroll
        for (int j = 0; j < 4; ++j) Am[tx + 16 * i][ty + 16 * j] = acc[i][j];
    __syncthreads();
    if (threadIdx.x < 64) {
        int v = threadIdx.x;
        float m = -1e30f;
        for (int w = 0; w < NW; ++w) m = fmaxf(m, Am[w][v]);
        float s = 0.f;
        for (int w = 0; w < NW; ++w) { float e = __expf((Am[w][v] - m) * INV_TAU); Pm[w][v] = e; s += e; }
        float r = 1.f / s;
        for (int w = 0; w < NW; ++w) Pm[w][v] *= r;
    }
    __syncthreads();
    float mm[5][4] = {};
    for (int w = 0; w < NW; ++w) {
        float a[5], b[4];
        #pragma unroll
        for (int i = 0; i < 5; ++i) a[i] = Wl[w * NW + tx + 16 * i];
        #pragma unroll
        for (int j = 0; j < 4; ++j) b[j] = Pm[w][ty + 16 * j];
        #pragma unroll
        for (int i = 0; i < 5; ++i)
            #pragma unroll
            for (int j = 0; j < 4; ++j) mm[i][j] += a[i] * b[j];
    }
    #pragma unroll
    for (int j = 0; j < 4; ++j) {
        float p = 0.f;
        #pragma unroll
        for (int i = 0; i < 5; ++i) p += mm[i][j] * Am[tx + 16 * i][ty + 16 * j];
        for (int o = 8; o; o >>= 1) p += __shfl_xor(p, o, 16);
        if (tx == 0) sim[t * BS + v0 + ty + 16 * j] += 0.25f * p;
    }
}

// ---------------- K4: sentence_frame (unchanged fp32) ----------------
__global__ __launch_bounds__(256, 2) void k_sent_frame(
    const float* __restrict__ sent, const float* __restrict__ ff,
    const float* __restrict__ Fl, float* __restrict__ sim)
{
    __shared__ __align__(16) float Ss[64][36];
    __shared__ __align__(16) float Fs[64][36];
    __shared__ float Bm[64][65];
    __shared__ float Pm[64][65];
    int tx = threadIdx.x & 15, ty = threadIdx.x >> 4;
    int v = blockIdx.y, t0 = blockIdx.x * 64;
    const float* ffv = ff + v * NF * DD;
    float acc[4][4] = {};
    for (int kk = 0; kk < DD; kk += 32) {
        for (int l = threadIdx.x; l < 64 * 32; l += 256) {
            int r = l >> 5, k = l & 31;
            Ss[r][k] = sent[(t0 + r) * DD + kk + k];
            Fs[r][k] = ffv[r * DD + kk + k];
        }
        __syncthreads();
        #pragma unroll
        for (int k = 0; k < 32; k += 4) {
            float4 a[4], b[4];
            #pragma unroll
            for (int i = 0; i < 4; ++i) a[i] = *(const float4*)&Ss[tx + 16 * i][k];
            #pragma unroll
            for (int j = 0; j < 4; ++j) b[j] = *(const float4*)&Fs[ty + 16 * j][k];
            #pragma unroll
            for (int i = 0; i < 4; ++i)
                #pragma unroll
                for (int j = 0; j < 4; ++j)
                    acc[i][j] += a[i].x * b[j].x + a[i].y * b[j].y + a[i].z * b[j].z + a[i].w * b[j].w;
        }
        __syncthreads();
    }
    #pragma unroll
    for (int i = 0; i < 4; ++i)
        #pragma unroll
        for (int j = 0; j < 4; ++j) Bm[tx + 16 * i][ty + 16 * j] = acc[i][j];
    __syncthreads();
    if (threadIdx.x < 64) {
        int r = threadIdx.x;
        float m = -1e30f;
        for (int f = 0; f < NF; ++f) m = fmaxf(m, Bm[r][f]);
        float s = 0.f;
        for (int f = 0; f < NF; ++f) { float e = __expf((Bm[r][f] - m) * INV_TAU); Pm[r][f] = e; s += e; }
        float rr = 1.f / s;
        for (int f = 0; f < NF; ++f) Pm[r][f] *= rr;
    }
    __syncthreads();
    float nn[4][4] = {};
    for (int f = 0; f < NF; ++f) {
        float a[4], b[4];
        #pragma unroll
        for (int i = 0; i < 4; ++i) a[i] = Pm[ty + 16 * i][f];
        #pragma unroll
        for (int j = 0; j < 4; ++j) b[j] = Fl[f * NF + tx + 16 * j];
        #pragma unroll
        for (int i = 0; i < 4; ++i)
            #pragma unroll
            for (int j = 0; j < 4; ++j) nn[i][j] += a[i] * b[j];
    }
    #pragma unroll
    for (int i = 0; i < 4; ++i) {
        float p = 0.f;
        #pragma unroll
        for (int j = 0; j < 4; ++j) p += nn[i][j] * Bm[ty + 16 * i][tx + 16 * j];
        for (int o = 8; o; o >>= 1) p += __shfl_xor(p, o, 16);
        if (tx == 0) sim[(t0 + ty + 16 * i) * BS + v] += 0.25f * p;
    }
}

// ---------------- K5: frame_word — MFMA split-bf16 GEMM + fused post ----------------
// grid (128,128): (v,t). S = wl_t[80,768] @ ff_v[64,768]^T via 3-pass split-bf16 MFMA.
__global__ __launch_bounds__(256, 2) void k_frame_word(
    const u16* __restrict__ wl_hi, const u16* __restrict__ wl_lo,
    const u16* __restrict__ ff_hi, const u16* __restrict__ ff_lo,
    const float* __restrict__ Wm, const float* __restrict__ Fm,
    const float* __restrict__ F2, const float* __restrict__ Wm2,
    float* __restrict__ sim)
{
    // staging: A_hi[80][64] | A_lo[80][64] | B_hi[64][64] | B_lo[64][64]  (bf16, XOR-swizzled)
    __shared__ union {
        u16 stage[18432];
        struct {
            float P[80][65];
            float redm[4][64], reds[4][64];
            float wlv[64], flv[80], smw[64], smf[80];
            float s2f, v2w;
        } post;
    } sh;
    __shared__ float S[80][65];

    const int tid = threadIdx.x;
    const int lane = tid & 63, wid = tid >> 6;
    const int v = blockIdx.x, t = blockIdx.y;

    f32x4 acc[5];
    #pragma unroll
    for (int i = 0; i < 5; ++i) acc[i] = (f32x4){0.f, 0.f, 0.f, 0.f};

    // staging geometry: each global_load_lds covers 8 rows (8 lanes/row x 16B).
    // LDS is linear (row*128B + slot*16B); read side XORs slot with (row&7); so
    // source k-group = slot ^ (row&7)  [rule 21: inverse-swizzled source].
    const int r8 = lane >> 3, s8 = lane & 7;
    const int gk = s8 ^ r8;

    for (int kk = 0; kk < DD; kk += 64) {
        for (int seg = wid; seg < 36; seg += 4) {
            const u16* src;
            int ldsoff;
            if (seg < 10) {
                int g = seg, row = g * 8 + r8;
                src = wl_hi + (size_t)(t * NW + row) * DD + kk + gk * 8;
                ldsoff = g * 512;
            } else if (seg < 20) {
                int g = seg - 10, row = g * 8 + r8;
                src = wl_lo + (size_t)(t * NW + row) * DD + kk + gk * 8;
                ldsoff = 5120 + g * 512;
            } else if (seg < 28) {
                int g = seg - 20, row = g * 8 + r8;
                src = ff_hi + (size_t)(v * NF + row) * DD + kk + gk * 8;
                ldsoff = 10240 + g * 512;
            } else {
                int g = seg - 28, row = g * 8 + r8;
                src = ff_lo + (size_t)(v * NF + row) * DD + kk + gk * 8;
                ldsoff = 14336 + g * 512;
            }
            gload_lds16(src, (void*)&sh.stage[ldsoff]);
        }
        __syncthreads();
        const u16* st = sh.stage;
        #pragma unroll
        for (int ks = 0; ks < 2; ++ks) {
            const int sl = (ks << 2) + (lane >> 4);
            bf16x8 afh[5], afl[5], bfh, bfl;
            #pragma unroll
            for (int i = 0; i < 5; ++i) {
                int row = (lane & 15) + 16 * i;
                int off = row * 64 + ((sl ^ (row & 7)) << 3);
                afh[i] = *(const bf16x8*)&st[off];
                afl[i] = *(const bf16x8*)&st[5120 + off];
            }
            {
                int row = (lane & 15) + 16 * wid;
                int off = row * 64 + ((sl ^ (row & 7)) << 3);
                bfh = *(const bf16x8*)&st[10240 + off];
                bfl = *(const bf16x8*)&st[14336 + off];
            }
            #pragma unroll
            for (int i = 0; i < 5; ++i) {
                acc[i] = __builtin_amdgcn_mfma_f32_16x16x32_bf16(afh[i], bfh, acc[i], 0, 0, 0);
                acc[i] = __builtin_amdgcn_mfma_f32_16x16x32_bf16(afh[i], bfl, acc[i], 0, 0, 0);
                acc[i] = __builtin_amdgcn_mfma_f32_16x16x32_bf16(afl[i], bfh, acc[i], 0, 0, 0);
            }
        }
        __syncthreads();
    }

    // write S: D-frag mapping col=lane&15, row=(lane>>4)*4+reg  [m89-verified]
    #pragma unroll
    for (int i = 0; i < 5; ++i)
        #pragma unroll
        for (int r = 0; r < 4; ++r)
            S[16 * i + ((lane >> 4) << 2) + r][(lane & 15) + (wid << 4)] = acc[i][r];
    __syncthreads();

    // ---- column softmax over w per f -> P[w][f] (4-way split over q) ----
    {
        const int f = tid & 63, q = tid >> 6;
        const int w0 = q * 20;
        float m = -1e30f;
        for (int w = w0; w < w0 + 20; ++w) m = fmaxf(m, S[w][f]);
        float s = 0.f;
        for (int w = w0; w < w0 + 20; ++w) {
            float e = __expf((S[w][f] - m) * INV_TAU);
            sh.post.P[w][f] = e; s += e;
        }
        sh.post.redm[q][f] = m; sh.post.reds[q][f] = s;
        __syncthreads();
        float M = -1e30f;
        #pragma unroll
        for (int qq = 0; qq < 4; ++qq) M = fmaxf(M, sh.post.redm[qq][f]);
        float Dn = 0.f;
        #pragma unroll
        for (int qq = 0; qq < 4; ++qq) Dn += sh.post.reds[qq][f] * __expf((sh.post.redm[qq][f] - M) * INV_TAU);
        float sc = __expf((m - M) * INV_TAU) / Dn;
        for (int w = w0; w < w0 + 20; ++w) sh.post.P[w][f] *= sc;
    }
    __syncthreads();

    // ---- word mix: mixed[u][f] = sum_w Wm[w][u]*P[w][f]; word_level[f] = sum_u mixed*S ----
    {
        const int tx = tid & 15, ty = tid >> 4;
        float mm[5][4] = {};
        for (int w = 0; w < NW; ++w) {
            float b0 = sh.post.P[w][ty], b1 = sh.post.P[w][ty + 16];
            float b2 = sh.post.P[w][ty + 32], b3 = sh.post.P[w][ty + 48];
            #pragma unroll
            for (int i = 0; i < 5; ++i) {
                float a = Wm[w * NW + tx + 16 * i];
                mm[i][0] += a * b0; mm[i][1] += a * b1; mm[i][2] += a * b2; mm[i][3] += a * b3;
            }
        }
        #pragma unroll
        for (int j = 0; j < 4; ++j) {
            float p = 0.f;
            #pragma unroll
            for (int i = 0; i < 5; ++i) p += mm[i][j] * S[tx + 16 * i][ty + 16 * j];
            #pragma unroll
            for (int o = 8; o; o >>= 1) p += __shfl_xor(p, o, 16);
            if (tx == 0) sh.post.wlv[ty + 16 * j] = p;
        }
    }
    __syncthreads();

    // ---- row softmax over f per w -> P (overwrite; word mix done reading) ----
    if (tid < 160) {
        const int w = tid >> 1, h = tid & 1;
        const int f0 = h * 32;
        float m = -1e30f;
        for (int c = 0; c < 32; ++c) m = fmaxf(m, S[w][f0 + c]);
        m = fmaxf(m, __shfl_xor(m, 1));
        float s = 0.f;
        for (int c = 0; c < 32; ++c) {
            float e = __expf((S[w][f0 + c] - m) * INV_TAU);
            sh.post.P[w][f0 + c] = e; s += e;
        }
        s += __shfl_xor(s, 1);
        float r = 1.f / s;
        for (int c = 0; c < 32; ++c) sh.post.P[w][f0 + c] *= r;
    }
    __syncthreads();

    // ---- frame mix: mF[w][f'] = sum_f P[w][f]*Fm[f][f']; frame_level[w] = sum_f' mF*S ----
    {
        const int tx = tid & 15, ty = tid >> 4;
        float nn[5][4] = {};
        for (int f = 0; f < NF; ++f) {
            float b0 = Fm[f * NF + tx], b1 = Fm[f * NF + tx + 16];
            float b2 = Fm[f * NF + tx + 32], b3 = Fm[f * NF + tx + 48];
            #pragma unroll
            for (int i = 0; i < 5; ++i) {
                float a = sh.post.P[ty + 16 * i][f];
                nn[i][0] += a * b0; nn[i][1] += a * b1; nn[i][2] += a * b2; nn[i][3] += a * b3;
            }
        }
        #pragma unroll
        for (int i = 0; i < 5; ++i) {
            float p = 0.f;
            #pragma unroll
            for (int j = 0; j < 4; ++j) p += nn[i][j] * S[ty + 16 * i][tx + 16 * j];
            #pragma unroll
            for (int o = 8; o; o >>= 1) p += __shfl_xor(p, o, 16);
            if (tx == 0) sh.post.flv[ty + 16 * i] = p;
        }
    }
    __syncthreads();

    // ---- final softmaxes (wave-parallel, in-register) ----
    if (wid == 0) {
        float x = sh.post.wlv[lane];
        float m = x;
        #pragma unroll
        for (int o = 32; o; o >>= 1) m = fmaxf(m, __shfl_xor(m, o));
        float e = __expf((x - m) * INV_TAU);
        float s = e;
        #pragma unroll
        for (int o = 32; o; o >>= 1) s += __shfl_xor(s, o);
        sh.post.smw[lane] = e / s;
    } else if (wid == 1) {
        float x0 = sh.post.flv[lane];
        float x1 = (lane < 16) ? sh.post.flv[64 + lane] : -1e30f;
        float m = fmaxf(x0, x1);
        #pragma unroll
        for (int o = 32; o; o >>= 1) m = fmaxf(m, __shfl_xor(m, o));
        float e0 = __expf((x0 - m) * INV_TAU);
        float e1 = (lane < 16) ? __expf((x1 - m) * INV_TAU) : 0.f;
        float s = e0 + e1;
        #pragma unroll
        for (int o = 32; o; o >>= 1) s += __shfl_xor(s, o);
        sh.post.smf[lane] = e0 / s;
        if (lane < 16) sh.post.smf[64 + lane] = e1 / s;
    }
    __syncthreads();

    if (wid == 0) {                 // sent2frame
        float g = 0.f;
        for (int f = 0; f < NF; ++f) g += sh.post.smw[f] * F2[f * NF + lane];
        float p = g * sh.post.wlv[lane];
        #pragma unroll
        for (int o = 32; o; o >>= 1) p += __shfl_xor(p, o);
        if (lane == 0) sh.post.s2f = p;
    } else if (wid == 1) {          // video2word
        float g = 0.f;
        for (int w = 0; w < NW; ++w) g += sh.post.smf[w] * Wm2[w * NW + lane];
        float p = g * sh.post.flv[lane];
        if (lane < 16) {
            float g2 = 0.f;
            for (int w = 0; w < NW; ++w) g2 += sh.post.smf[w] * Wm2[w * NW + 64 + lane];
            p += g2 * sh.post.flv[64 + lane];
        }
        #pragma unroll
        for (int o = 32; o; o >>= 1) p += __shfl_xor(p, o);
        if (lane == 0) sh.post.v2w = p;
    }
    __syncthreads();
    if (tid == 0) sim[t * BS + v] += 0.125f * (sh.post.s2f + sh.post.v2w);
}

// ---------------- K6: loss from sim ----------------
__global__ __launch_bounds__(256) void k_loss(const float* __restrict__ sim, float* __restrict__ out)
{
    __shared__ float S[BS][BS + 1];
    __shared__ float lr[BS], lc[BS];
    for (int l = threadIdx.x; l < BS * BS; l += 256) {
        int r = l >> 7, c = l & 127;
        S[r][c] = sim[l];
    }
    __syncthreads();
    int tid = threadIdx.x;
    if (tid < BS) {
        float m = -1e30f;
        for (int c = 0; c < BS; ++c) m = fmaxf(m, S[tid][c]);
        float s = 0.f;
        for (int c = 0; c < BS; ++c) s += __expf(S[tid][c] - m);
        lr[tid] = m + __logf(s);
    } else {
        int c = tid - BS;
        float m = -1e30f;
        for (int r = 0; r < BS; ++r) m = fmaxf(m, S[r][c]);
        float s = 0.f;
        for (int r = 0; r < BS; ++r) s += __expf(S[r][c] - m);
        lc[c] = m + __logf(s);
    }
    __syncthreads();
    if (tid == 0) {
        float a = 0.f;
        for (int i = 0; i < BS; ++i) a += S[i][i] - 0.5f * lr[i] - 0.5f * lc[i];
        out[0] = -a / (float)BS;
    }
}

extern "C" void kernel_launch(void* const* d_in, const int* in_sizes, int n_in,
                              void* d_out, int out_size, void* d_ws, size_t ws_size,
                              hipStream_t stream)
{
    const float* traj = (const float*)d_in[0];
    const float* ff   = (const float*)d_in[1];
    const float* sent = (const float*)d_in[2];
    const float* wf   = (const float*)d_in[3];
    const float* G    = (const float*)d_in[4];
    const float* Wl   = (const float*)d_in[5];
    const float* Fl   = (const float*)d_in[6];
    const float* L    = (const float*)d_in[7];
    const float* Fm   = (const float*)d_in[8];
    const float* Wm   = (const float*)d_in[9];
    const float* F2   = (const float*)d_in[10];
    const float* Wm2  = (const float*)d_in[11];
    float* out = (float*)d_out;
    char* base = (char*)d_ws;

    // ws layout (bytes)
    float* sg    = (float*)(base);                      // 128*768*4   = 393216
    float* sim   = (float*)(base + 393216);             // 128*128*4   = 65536
    u16*   wl_hi = (u16*)(base + 458752);               // 10240*768*2 = 15728640
    u16*   wl_lo = (u16*)(base + 16187392);             // 15728640
    u16*   ff_hi = (u16*)(base + 31916032);             // 128*64*768*2 = 12582912
    u16*   ff_lo = (u16*)(base + 44498944);             // 12582912 -> 57081856 total

    hipLaunchKernelGGL(k_sent_global, dim3(BS * DD / 256), dim3(256), 0, stream, sent, G, sg);
    hipLaunchKernelGGL(k_traj_sent, dim3(8, 8), dim3(256), 0, stream, sg, traj, sim);
    hipLaunchKernelGGL(k_wl, dim3(12, 160), dim3(256), 0, stream, wf, L, wl_hi, wl_lo);
    hipLaunchKernelGGL(k_ffsplit, dim3(BS * NF * DD / 1024), dim3(256), 0, stream, ff, ff_hi, ff_lo);
    hipLaunchKernelGGL(k_video_word, dim3(2, BS), dim3(256), 0, stream, wf, traj, Wl, sim);
    hipLaunchKernelGGL(k_sent_frame, dim3(2, BS), dim3(256), 0, stream, sent, ff, Fl, sim);
    hipLaunchKernelGGL(k_frame_word, dim3(BS, BS), dim3(256), 0, stream,
                       wl_hi, wl_lo, ff_hi, ff_lo, Wm, Fm, F2, Wm2, sim);
    hipLaunchKernelGGL(k_loss, dim3(1), dim3(256), 0, stream, sim, out);
}

// Round 3
// 1533.430 us; speedup vs baseline: 3.7918x; 1.3216x over previous
//
#include <hip/hip_runtime.h>
#include <math.h>

#define BS 128
#define NW 80
#define NF 64
#define DD 768
#define INV_TAU 100.0f

typedef unsigned short u16;
typedef unsigned int u32;
typedef __attribute__((ext_vector_type(8))) short bf16x8;
typedef __attribute__((ext_vector_type(4))) float f32x4;

__device__ __forceinline__ u16 f2bf(float x) {
    unsigned b = __float_as_uint(x);
    return (u16)((b + 0x7fffu + ((b >> 16) & 1u)) >> 16);
}
__device__ __forceinline__ float bf2f(u16 h) { return __uint_as_float(((unsigned)h) << 16); }

__device__ __forceinline__ void gload_lds16(const void* gsrc, void* ldst) {
    __builtin_amdgcn_global_load_lds(
        (const __attribute__((address_space(1))) unsigned int*)gsrc,
        (__attribute__((address_space(3))) unsigned int*)ldst, 16, 0, 0);
}

// ---------------- K1: sg = sentence_output @ global_mat_weight ----------------
__global__ __launch_bounds__(256) void k_sent_global(
    const float* __restrict__ sent, const float* __restrict__ G, float* __restrict__ sg)
{
    int idx = blockIdx.x * 256 + threadIdx.x;
    int t = idx / DD, e = idx % DD;
    const float* srow = sent + t * DD;
    float acc = 0.f;
    #pragma unroll 4
    for (int d = 0; d < DD; ++d) acc += srow[d] * G[d * DD + e];
    sg[idx] = acc;
}

// ---------------- K1b: sim = 0.25 * sg @ traj^T (first writer of sim) ----------------
__global__ __launch_bounds__(256) void k_traj_sent(
    const float* __restrict__ sg, const float* __restrict__ traj, float* __restrict__ sim)
{
    __shared__ float ss[16][33], tt[16][33];
    int tx = threadIdx.x & 15, ty = threadIdx.x >> 4;
    int t0 = blockIdx.y * 16, v0 = blockIdx.x * 16;
    float acc = 0.f;
    for (int kk = 0; kk < DD; kk += 32) {
        for (int l = threadIdx.x; l < 16 * 32; l += 256) {
            int r = l >> 5, c = l & 31;
            ss[r][c] = sg[(t0 + r) * DD + kk + c];
            tt[r][c] = traj[(v0 + r) * DD + kk + c];
        }
        __syncthreads();
        #pragma unroll
        for (int k = 0; k < 32; ++k) acc += ss[ty][k] * tt[tx][k];
        __syncthreads();
    }
    sim[(t0 + ty) * BS + v0 + tx] = 0.25f * acc;
}

// ---------------- K_prepw: WmT[80][96] hi/lo (zero-padded), FmT[64][64] hi/lo ----------------
__global__ __launch_bounds__(256) void k_prepw(
    const float* __restrict__ Wm, const float* __restrict__ Fm,
    u16* __restrict__ WmT_hi, u16* __restrict__ WmT_lo,
    u16* __restrict__ FmT_hi, u16* __restrict__ FmT_lo)
{
    int gid = blockIdx.x * 256 + threadIdx.x;
    if (gid < 80 * 96) {
        int u = gid / 96, w = gid % 96;
        float x = (w < 80) ? Wm[w * 80 + u] : 0.f;
        u16 h = f2bf(x);
        WmT_hi[gid] = h; WmT_lo[gid] = f2bf(x - bf2f(h));
    } else if (gid < 80 * 96 + 64 * 64) {
        int j = gid - 80 * 96;
        int fp = j >> 6, f = j & 63;
        float x = Fm[f * 64 + fp];
        u16 h = f2bf(x);
        FmT_hi[j] = h; FmT_lo[j] = f2bf(x - bf2f(h));
    }
}

// ---------------- K2b: split ff to bf16 hi/lo ----------------
__global__ __launch_bounds__(256) void k_ffsplit(
    const float* __restrict__ x, u16* __restrict__ hi, u16* __restrict__ lo)
{
    int i = blockIdx.x * 256 + threadIdx.x;
    float4 f = *(const float4*)&x[(size_t)i * 4];
    ushort4 h, l;
    h.x = f2bf(f.x); l.x = f2bf(f.x - bf2f(h.x));
    h.y = f2bf(f.y); l.y = f2bf(f.y - bf2f(h.y));
    h.z = f2bf(f.z); l.z = f2bf(f.z - bf2f(h.z));
    h.w = f2bf(f.w); l.w = f2bf(f.w - bf2f(h.w));
    *(ushort4*)&hi[(size_t)i * 4] = h;
    *(ushort4*)&lo[(size_t)i * 4] = l;
}

// ---------------- K2: wl = wf @ L via split-bf16 MFMA (reg-staged) ----------------
// grid (6, 80): 128x128 tile, K-chunk 64, 3-pass split. Outputs wl hi/lo bf16.
__global__ __launch_bounds__(256, 2) void k_wl(
    const float* __restrict__ wf, const float* __restrict__ L,
    u16* __restrict__ wl_hi, u16* __restrict__ wl_lo)
{
    __shared__ u16 Ah[128][72], Al[128][72];   // [m][k], pad 72
    __shared__ u16 Bh[128][72], Bl[128][72];   // [n][k], pad 72, k XOR ((n&7)<<3)
    const int tid = threadIdx.x;
    const int lane = tid & 63, wid = tid >> 6;
    const int m0 = blockIdx.y * 128, n0 = blockIdx.x * 128;

    f32x4 acc[2][8];
    #pragma unroll
    for (int i = 0; i < 2; ++i)
        #pragma unroll
        for (int j = 0; j < 8; ++j) acc[i][j] = (f32x4){0.f, 0.f, 0.f, 0.f};

    for (int kk = 0; kk < DD; kk += 64) {
        // stage A (wf tile), convert to hi/lo
        #pragma unroll
        for (int p = 0; p < 8; ++p) {
            int row = p * 16 + (tid >> 4), c4 = tid & 15;
            float4 v = *(const float4*)&wf[(size_t)(m0 + row) * DD + kk + c4 * 4];
            ushort4 h, l;
            h.x = f2bf(v.x); l.x = f2bf(v.x - bf2f(h.x));
            h.y = f2bf(v.y); l.y = f2bf(v.y - bf2f(h.y));
            h.z = f2bf(v.z); l.z = f2bf(v.z - bf2f(h.z));
            h.w = f2bf(v.w); l.w = f2bf(v.w - bf2f(h.w));
            *(ushort4*)&Ah[row][c4 * 4] = h;
            *(ushort4*)&Al[row][c4 * 4] = l;
        }
        // stage B (L tile), transpose + convert, XOR-swizzled k
        #pragma unroll
        for (int p = 0; p < 8; ++p) {
            int kr = p * 8 + (tid >> 5), c4 = tid & 31;
            float4 v = *(const float4*)&L[(size_t)(kk + kr) * DD + n0 + c4 * 4];
            #pragma unroll
            for (int jj = 0; jj < 4; ++jj) {
                int n = c4 * 4 + jj;
                float x = (jj == 0) ? v.x : (jj == 1) ? v.y : (jj == 2) ? v.z : v.w;
                u16 h = f2bf(x);
                int ka = kr ^ ((n & 7) << 3);
                Bh[n][ka] = h;
                Bl[n][ka] = f2bf(x - bf2f(h));
            }
        }
        __syncthreads();
        #pragma unroll
        for (int ks = 0; ks < 2; ++ks) {
            int koff = ks * 32 + (lane >> 4) * 8;
            bf16x8 ah[2], al[2];
            #pragma unroll
            for (int i = 0; i < 2; ++i) {
                int row = wid * 32 + 16 * i + (lane & 15);
                ah[i] = *(const bf16x8*)&Ah[row][koff];
                al[i] = *(const bf16x8*)&Al[row][koff];
            }
            #pragma unroll
            for (int j = 0; j < 8; ++j) {
                int n = 16 * j + (lane & 15);
                int kb = koff ^ ((n & 7) << 3);
                bf16x8 bh = *(const bf16x8*)&Bh[n][kb];
                bf16x8 bl = *(const bf16x8*)&Bl[n][kb];
                #pragma unroll
                for (int i = 0; i < 2; ++i) {
                    acc[i][j] = __builtin_amdgcn_mfma_f32_16x16x32_bf16(ah[i], bh, acc[i][j], 0, 0, 0);
                    acc[i][j] = __builtin_amdgcn_mfma_f32_16x16x32_bf16(ah[i], bl, acc[i][j], 0, 0, 0);
                    acc[i][j] = __builtin_amdgcn_mfma_f32_16x16x32_bf16(al[i], bh, acc[i][j], 0, 0, 0);
                }
            }
        }
        __syncthreads();
    }
    #pragma unroll
    for (int i = 0; i < 2; ++i)
        #pragma unroll
        for (int j = 0; j < 8; ++j)
            #pragma unroll
            for (int r = 0; r < 4; ++r) {
                float x = acc[i][j][r];
                int row = m0 + wid * 32 + 16 * i + ((lane >> 4) << 2) + r;
                int col = n0 + 16 * j + (lane & 15);
                size_t idx = (size_t)row * DD + col;
                u16 h = f2bf(x);
                wl_hi[idx] = h;
                wl_lo[idx] = f2bf(x - bf2f(h));
            }
}

// ---------------- K3: video_word (fp32, unchanged) ----------------
__global__ __launch_bounds__(256, 2) void k_video_word(
    const float* __restrict__ wf, const float* __restrict__ traj,
    const float* __restrict__ Wl, float* __restrict__ sim)
{
    __shared__ __align__(16) float As[NW][36];
    __shared__ __align__(16) float Bs[64][36];
    __shared__ float Am[NW][65];
    __shared__ float Pm[NW][65];
    int tx = threadIdx.x & 15, ty = threadIdx.x >> 4;
    int t = blockIdx.y, v0 = blockIdx.x * 64;
    const float* wft = wf + t * NW * DD;
    float acc[5][4] = {};
    for (int kk = 0; kk < DD; kk += 32) {
        for (int l = threadIdx.x; l < NW * 32; l += 256) {
            int w = l >> 5, k = l & 31;
            As[w][k] = wft[w * DD + kk + k];
        }
        for (int l = threadIdx.x; l < 64 * 32; l += 256) {
            int v = l >> 5, k = l & 31;
            Bs[v][k] = traj[(v0 + v) * DD + kk + k];
        }
        __syncthreads();
        #pragma unroll
        for (int k = 0; k < 32; k += 4) {
            float4 a[5], b[4];
            #pragma unroll
            for (int i = 0; i < 5; ++i) a[i] = *(const float4*)&As[tx + 16 * i][k];
            #pragma unroll
            for (int j = 0; j < 4; ++j) b[j] = *(const float4*)&Bs[ty + 16 * j][k];
            #pragma unroll
            for (int i = 0; i < 5; ++i)
                #pragma unroll
                for (int j = 0; j < 4; ++j)
                    acc[i][j] += a[i].x * b[j].x + a[i].y * b[j].y + a[i].z * b[j].z + a[i].w * b[j].w;
        }
        __syncthreads();
    }
    #pragma unroll
    for (int i = 0; i < 5; ++i)
        #pragma unroll
        for (int j = 0; j < 4; ++j) Am[tx + 16 * i][ty + 16 * j] = acc[i][j];
    __syncthreads();
    if (threadIdx.x < 64) {
        int v = threadIdx.x;
        float m = -1e30f;
        for (int w = 0; w < NW; ++w) m = fmaxf(m, Am[w][v]);
        float s = 0.f;
        for (int w = 0; w < NW; ++w) { float e = __expf((Am[w][v] - m) * INV_TAU); Pm[w][v] = e; s += e; }
        float r = 1.f / s;
        for (int w = 0; w < NW; ++w) Pm[w][v] *= r;
    }
    __syncthreads();
    float mm[5][4] = {};
    for (int w = 0; w < NW; ++w) {
        float a[5], b[4];
        #pragma unroll
        for (int i = 0; i < 5; ++i) a[i] = Wl[w * NW + tx + 16 * i];
        #pragma unroll
        for (int j = 0; j < 4; ++j) b[j] = Pm[w][ty + 16 * j];
        #pragma unroll
        for (int i = 0; i < 5; ++i)
            #pragma unroll
            for (int j = 0; j < 4; ++j) mm[i][j] += a[i] * b[j];
    }
    #pragma unroll
    for (int j = 0; j < 4; ++j) {
        float p = 0.f;
        #pragma unroll
        for (int i = 0; i < 5; ++i) p += mm[i][j] * Am[tx + 16 * i][ty + 16 * j];
        for (int o = 8; o; o >>= 1) p += __shfl_xor(p, o, 16);
        if (tx == 0) sim[t * BS + v0 + ty + 16 * j] += 0.25f * p;
    }
}

// ---------------- K4: sentence_frame (fp32, unchanged) ----------------
__global__ __launch_bounds__(256, 2) void k_sent_frame(
    const float* __restrict__ sent, const float* __restrict__ ff,
    const float* __restrict__ Fl, float* __restrict__ sim)
{
    __shared__ __align__(16) float Ss[64][36];
    __shared__ __align__(16) float Fs[64][36];
    __shared__ float Bm[64][65];
    __shared__ float Pm[64][65];
    int tx = threadIdx.x & 15, ty = threadIdx.x >> 4;
    int v = blockIdx.y, t0 = blockIdx.x * 64;
    const float* ffv = ff + v * NF * DD;
    float acc[4][4] = {};
    for (int kk = 0; kk < DD; kk += 32) {
        for (int l = threadIdx.x; l < 64 * 32; l += 256) {
            int r = l >> 5, k = l & 31;
            Ss[r][k] = sent[(t0 + r) * DD + kk + k];
            Fs[r][k] = ffv[r * DD + kk + k];
        }
        __syncthreads();
        #pragma unroll
        for (int k = 0; k < 32; k += 4) {
            float4 a[4], b[4];
            #pragma unroll
            for (int i = 0; i < 4; ++i) a[i] = *(const float4*)&Ss[tx + 16 * i][k];
            #pragma unroll
            for (int j = 0; j < 4; ++j) b[j] = *(const float4*)&Fs[ty + 16 * j][k];
            #pragma unroll
            for (int i = 0; i < 4; ++i)
                #pragma unroll
                for (int j = 0; j < 4; ++j)
                    acc[i][j] += a[i].x * b[j].x + a[i].y * b[j].y + a[i].z * b[j].z + a[i].w * b[j].w;
        }
        __syncthreads();
    }
    #pragma unroll
    for (int i = 0; i < 4; ++i)
        #pragma unroll
        for (int j = 0; j < 4; ++j) Bm[tx + 16 * i][ty + 16 * j] = acc[i][j];
    __syncthreads();
    if (threadIdx.x < 64) {
        int r = threadIdx.x;
        float m = -1e30f;
        for (int f = 0; f < NF; ++f) m = fmaxf(m, Bm[r][f]);
        float s = 0.f;
        for (int f = 0; f < NF; ++f) { float e = __expf((Bm[r][f] - m) * INV_TAU); Pm[r][f] = e; s += e; }
        float rr = 1.f / s;
        for (int f = 0; f < NF; ++f) Pm[r][f] *= rr;
    }
    __syncthreads();
    float nn[4][4] = {};
    for (int f = 0; f < NF; ++f) {
        float a[4], b[4];
        #pragma unroll
        for (int i = 0; i < 4; ++i) a[i] = Pm[ty + 16 * i][f];
        #pragma unroll
        for (int j = 0; j < 4; ++j) b[j] = Fl[f * NF + tx + 16 * j];
        #pragma unroll
        for (int i = 0; i < 4; ++i)
            #pragma unroll
            for (int j = 0; j < 4; ++j) nn[i][j] += a[i] * b[j];
    }
    #pragma unroll
    for (int i = 0; i < 4; ++i) {
        float p = 0.f;
        #pragma unroll
        for (int j = 0; j < 4; ++j) p += nn[i][j] * Bm[ty + 16 * i][tx + 16 * j];
        for (int o = 8; o; o >>= 1) p += __shfl_xor(p, o, 16);
        if (tx == 0) sim[(t0 + ty + 16 * i) * BS + v] += 0.25f * p;
    }
}

// ---------------- K5: frame_word — MFMA S-GEMM + MFMA mixes ----------------
__global__ __launch_bounds__(256, 3) void k_frame_word(
    const u16* __restrict__ wl_hi, const u16* __restrict__ wl_lo,
    const u16* __restrict__ ff_hi, const u16* __restrict__ ff_lo,
    const u16* __restrict__ WmT_hi, const u16* __restrict__ WmT_lo,
    const u16* __restrict__ FmT_hi, const u16* __restrict__ FmT_lo,
    const float* __restrict__ F2, const float* __restrict__ Wm2,
    float* __restrict__ sim)
{
    __shared__ __align__(16) union SH {
        u16 stage[18432];                      // 36864 B (GEMM phase)
        struct Post {
            float Sm[80][65];                  // 20800 (written after GEMM)
            union PU {
                struct { u16 Pt_hi[64][104]; u16 Pt_lo[64][104]; } m1;   // 26624
                struct { u16 P2_hi[80][72];  u16 P2_lo[80][72];  } m2;   // 23040
            } u;
            float redm[4][64], reds[4][64];
            float wlv[64], flv[80], flvp[4][80];
            float smw[64], smf[80];
            float s2f, v2w;
        } post;                                // 51912 B total
    } sh;

    const int tid = threadIdx.x;
    const int lane = tid & 63, wid = tid >> 6;
    const int col = lane & 15, grp = lane >> 4;
    const int v = blockIdx.x, t = blockIdx.y;

    f32x4 acc[5];
    #pragma unroll
    for (int i = 0; i < 5; ++i) acc[i] = (f32x4){0.f, 0.f, 0.f, 0.f};

    // ---- S-GEMM: S = wl_t[80x768] @ ff_v[64x768]^T, split-bf16 3-pass ----
    const int r8 = lane >> 3, s8 = lane & 7;
    const int gk = s8 ^ r8;

    for (int kk = 0; kk < DD; kk += 64) {
        for (int seg = wid; seg < 36; seg += 4) {
            const u16* src;
            int ldsoff;
            if (seg < 10) {
                int g = seg, row = g * 8 + r8;
                src = wl_hi + (size_t)(t * NW + row) * DD + kk + gk * 8;
                ldsoff = g * 512;
            } else if (seg < 20) {
                int g = seg - 10, row = g * 8 + r8;
                src = wl_lo + (size_t)(t * NW + row) * DD + kk + gk * 8;
                ldsoff = 5120 + g * 512;
            } else if (seg < 28) {
                int g = seg - 20, row = g * 8 + r8;
                src = ff_hi + (size_t)(v * NF + row) * DD + kk + gk * 8;
                ldsoff = 10240 + g * 512;
            } else {
                int g = seg - 28, row = g * 8 + r8;
                src = ff_lo + (size_t)(v * NF + row) * DD + kk + gk * 8;
                ldsoff = 14336 + g * 512;
            }
            gload_lds16(src, (void*)&sh.stage[ldsoff]);
        }
        __syncthreads();
        const u16* st = sh.stage;
        #pragma unroll
        for (int ks = 0; ks < 2; ++ks) {
            const int sl = (ks << 2) + grp;
            bf16x8 afh[5], afl[5], bfh, bfl;
            #pragma unroll
            for (int i = 0; i < 5; ++i) {
                int row = col + 16 * i;
                int off = row * 64 + ((sl ^ (row & 7)) << 3);
                afh[i] = *(const bf16x8*)&st[off];
                afl[i] = *(const bf16x8*)&st[5120 + off];
            }
            {
                int row = col + 16 * wid;
                int off = row * 64 + ((sl ^ (row & 7)) << 3);
                bfh = *(const bf16x8*)&st[10240 + off];
                bfl = *(const bf16x8*)&st[14336 + off];
            }
            #pragma unroll
            for (int i = 0; i < 5; ++i) {
                acc[i] = __builtin_amdgcn_mfma_f32_16x16x32_bf16(afh[i], bfh, acc[i], 0, 0, 0);
                acc[i] = __builtin_amdgcn_mfma_f32_16x16x32_bf16(afh[i], bfl, acc[i], 0, 0, 0);
                acc[i] = __builtin_amdgcn_mfma_f32_16x16x32_bf16(afl[i], bfh, acc[i], 0, 0, 0);
            }
        }
        __syncthreads();
    }

    // ---- write S to LDS (stage region now dead) ----
    #pragma unroll
    for (int i = 0; i < 5; ++i)
        #pragma unroll
        for (int r = 0; r < 4; ++r)
            sh.post.Sm[16 * i + (grp << 2) + r][col + (wid << 4)] = acc[i][r];
    __syncthreads();

    // ---- column softmax over w (per f), write P as bf16 hi/lo into Pt[f][w] ----
    {
        const int f = tid & 63, q = tid >> 6, w0 = q * 20;
        float m = -1e30f;
        for (int w = w0; w < w0 + 20; ++w) m = fmaxf(m, sh.post.Sm[w][f]);
        float s = 0.f;
        for (int w = w0; w < w0 + 20; ++w) s += __expf((sh.post.Sm[w][f] - m) * INV_TAU);
        sh.post.redm[q][f] = m; sh.post.reds[q][f] = s;
        __syncthreads();
        float M = -1e30f;
        #pragma unroll
        for (int qq = 0; qq < 4; ++qq) M = fmaxf(M, sh.post.redm[qq][f]);
        float Dn = 0.f;
        #pragma unroll
        for (int qq = 0; qq < 4; ++qq) Dn += sh.post.reds[qq][f] * __expf((sh.post.redm[qq][f] - M) * INV_TAU);
        float rDn = 1.f / Dn;
        #pragma unroll
        for (int mp = 0; mp < 10; ++mp) {
            int w = w0 + 2 * mp;
            float e0 = __expf((sh.post.Sm[w][f] - M) * INV_TAU) * rDn;
            float e1 = __expf((sh.post.Sm[w + 1][f] - M) * INV_TAU) * rDn;
            u16 h0 = f2bf(e0), h1 = f2bf(e1);
            u16 l0 = f2bf(e0 - bf2f(h0)), l1 = f2bf(e1 - bf2f(h1));
            *(u32*)&sh.post.u.m1.Pt_hi[f][w] = (u32)h0 | ((u32)h1 << 16);
            *(u32*)&sh.post.u.m1.Pt_lo[f][w] = (u32)l0 | ((u32)l1 << 16);
        }
        if (tid < 64) {       // zero k-pad w=80..95
            uint4 z = {0, 0, 0, 0};
            *(uint4*)&sh.post.u.m1.Pt_hi[tid][80] = z;
            *(uint4*)&sh.post.u.m1.Pt_hi[tid][88] = z;
            *(uint4*)&sh.post.u.m1.Pt_lo[tid][80] = z;
            *(uint4*)&sh.post.u.m1.Pt_lo[tid][88] = z;
        }
    }
    __syncthreads();

    // ---- mix1 (MFMA): D1[u][f] = sum_w WmT[u][w] * P[w][f]; wlv[f] = sum_u D1*S ----
    {
        f32x4 d1[5];
        #pragma unroll
        for (int i = 0; i < 5; ++i) d1[i] = (f32x4){0.f, 0.f, 0.f, 0.f};
        #pragma unroll
        for (int ks = 0; ks < 3; ++ks) {
            int baddr = (wid * 16 + col) * 104 + ks * 32 + grp * 8;
            bf16x8 bh = *(const bf16x8*)&sh.post.u.m1.Pt_hi[0][baddr];
            bf16x8 bl = *(const bf16x8*)&sh.post.u.m1.Pt_lo[0][baddr];
            #pragma unroll
            for (int i = 0; i < 5; ++i) {
                int aaddr = (16 * i + col) * 96 + ks * 32 + grp * 8;
                bf16x8 ah = *(const bf16x8*)&WmT_hi[aaddr];
                bf16x8 al = *(const bf16x8*)&WmT_lo[aaddr];
                d1[i] = __builtin_amdgcn_mfma_f32_16x16x32_bf16(ah, bh, d1[i], 0, 0, 0);
                d1[i] = __builtin_amdgcn_mfma_f32_16x16x32_bf16(ah, bl, d1[i], 0, 0, 0);
                d1[i] = __builtin_amdgcn_mfma_f32_16x16x32_bf16(al, bh, d1[i], 0, 0, 0);
            }
        }
        float p = 0.f;
        #pragma unroll
        for (int i = 0; i < 5; ++i)
            #pragma unroll
            for (int r = 0; r < 4; ++r)
                p += d1[i][r] * sh.post.Sm[16 * i + (grp << 2) + r][wid * 16 + col];
        p += __shfl_xor(p, 16);
        p += __shfl_xor(p, 32);
        if (lane < 16) sh.post.wlv[wid * 16 + lane] = p;
    }
    __syncthreads();

    // ---- row softmax over f (per w), write P2[w][f] bf16 hi/lo (overwrites Pt) ----
    if (tid < 160) {
        const int w = tid >> 1, h = tid & 1, f0 = h * 32;
        float m = -1e30f;
        for (int c = 0; c < 32; ++c) m = fmaxf(m, sh.post.Sm[w][f0 + c]);
        m = fmaxf(m, __shfl_xor(m, 1));
        float s = 0.f;
        for (int c = 0; c < 32; ++c) s += __expf((sh.post.Sm[w][f0 + c] - m) * INV_TAU);
        s += __shfl_xor(s, 1);
        float r = 1.f / s;
        #pragma unroll
        for (int mp = 0; mp < 16; ++mp) {
            int f = f0 + 2 * mp;
            float e0 = __expf((sh.post.Sm[w][f] - m) * INV_TAU) * r;
            float e1 = __expf((sh.post.Sm[w][f + 1] - m) * INV_TAU) * r;
            u16 h0 = f2bf(e0), h1 = f2bf(e1);
            u16 l0 = f2bf(e0 - bf2f(h0)), l1 = f2bf(e1 - bf2f(h1));
            *(u32*)&sh.post.u.m2.P2_hi[w][f] = (u32)h0 | ((u32)h1 << 16);
            *(u32*)&sh.post.u.m2.P2_lo[w][f] = (u32)l0 | ((u32)l1 << 16);
        }
    }
    __syncthreads();

    // ---- mix2 (MFMA): D2[w][f'] = sum_f P2[w][f] * FmT[f'][f]; flv[w] = sum_f' D2*S ----
    {
        f32x4 d2[5];
        #pragma unroll
        for (int i = 0; i < 5; ++i) d2[i] = (f32x4){0.f, 0.f, 0.f, 0.f};
        #pragma unroll
        for (int ks = 0; ks < 2; ++ks) {
            int baddr = (wid * 16 + col) * 64 + ks * 32 + grp * 8;
            bf16x8 bh = *(const bf16x8*)&FmT_hi[baddr];
            bf16x8 bl = *(const bf16x8*)&FmT_lo[baddr];
            #pragma unroll
            for (int i = 0; i < 5; ++i) {
                int aaddr = (16 * i + col) * 72 + ks * 32 + grp * 8;
                bf16x8 ah = *(const bf16x8*)&sh.post.u.m2.P2_hi[0][aaddr];
                bf16x8 al = *(const bf16x8*)&sh.post.u.m2.P2_lo[0][aaddr];
                d2[i] = __builtin_amdgcn_mfma_f32_16x16x32_bf16(ah, bh, d2[i], 0, 0, 0);
                d2[i] = __builtin_amdgcn_mfma_f32_16x16x32_bf16(ah, bl, d2[i], 0, 0, 0);
                d2[i] = __builtin_amdgcn_mfma_f32_16x16x32_bf16(al, bh, d2[i], 0, 0, 0);
            }
        }
        #pragma unroll
        for (int i = 0; i < 5; ++i)
            #pragma unroll
            for (int r = 0; r < 4; ++r) {
                int w = 16 * i + (grp << 2) + r;
                float p = d2[i][r] * sh.post.Sm[w][wid * 16 + col];
                p += __shfl_xor(p, 1);
                p += __shfl_xor(p, 2);
                p += __shfl_xor(p, 4);
                p += __shfl_xor(p, 8);
                if (col == 0) sh.post.flvp[wid][w] = p;
            }
    }
    __syncthreads();
    if (tid < 80)
        sh.post.flv[tid] = sh.post.flvp[0][tid] + sh.post.flvp[1][tid]
                         + sh.post.flvp[2][tid] + sh.post.flvp[3][tid];
    __syncthreads();

    // ---- final softmaxes (wave-parallel) ----
    if (wid == 0) {
        float x = sh.post.wlv[lane];
        float m = x;
        #pragma unroll
        for (int o = 32; o; o >>= 1) m = fmaxf(m, __shfl_xor(m, o));
        float e = __expf((x - m) * INV_TAU);
        float s = e;
        #pragma unroll
        for (int o = 32; o; o >>= 1) s += __shfl_xor(s, o);
        sh.post.smw[lane] = e / s;
    } else if (wid == 1) {
        float x0 = sh.post.flv[lane];
        float x1 = (lane < 16) ? sh.post.flv[64 + lane] : -1e30f;
        float m = fmaxf(x0, x1);
        #pragma unroll
        for (int o = 32; o; o >>= 1) m = fmaxf(m, __shfl_xor(m, o));
        float e0 = __expf((x0 - m) * INV_TAU);
        float e1 = (lane < 16) ? __expf((x1 - m) * INV_TAU) : 0.f;
        float s = e0 + e1;
        #pragma unroll
        for (int o = 32; o; o >>= 1) s += __shfl_xor(s, o);
        sh.post.smf[lane] = e0 / s;
        if (lane < 16) sh.post.smf[64 + lane] = e1 / s;
    }
    __syncthreads();

    if (wid == 0) {                 // sent2frame
        float g = 0.f;
        for (int f = 0; f < NF; ++f) g += sh.post.smw[f] * F2[f * NF + lane];
        float p = g * sh.post.wlv[lane];
        #pragma unroll
        for (int o = 32; o; o >>= 1) p += __shfl_xor(p, o);
        if (lane == 0) sh.post.s2f = p;
    } else if (wid == 1) {          // video2word
        float g = 0.f;
        for (int w = 0; w < NW; ++w) g += sh.post.smf[w] * Wm2[w * NW + lane];
        float p = g * sh.post.flv[lane];
        if (lane < 16) {
            float g2 = 0.f;
            for (int w = 0; w < NW; ++w) g2 += sh.post.smf[w] * Wm2[w * NW + 64 + lane];
            p += g2 * sh.post.flv[64 + lane];
        }
        #pragma unroll
        for (int o = 32; o; o >>= 1) p += __shfl_xor(p, o);
        if (lane == 0) sh.post.v2w = p;
    }
    __syncthreads();
    if (tid == 0) sim[t * BS + v] += 0.125f * (sh.post.s2f + sh.post.v2w);
}

// ---------------- K6: loss from sim ----------------
__global__ __launch_bounds__(256) void k_loss(const float* __restrict__ sim, float* __restrict__ out)
{
    __shared__ float S[BS][BS + 1];
    __shared__ float lr[BS], lc[BS];
    for (int l = threadIdx.x; l < BS * BS; l += 256) {
        int r = l >> 7, c = l & 127;
        S[r][c] = sim[l];
    }
    __syncthreads();
    int tid = threadIdx.x;
    if (tid < BS) {
        float m = -1e30f;
        for (int c = 0; c < BS; ++c) m = fmaxf(m, S[tid][c]);
        float s = 0.f;
        for (int c = 0; c < BS; ++c) s += __expf(S[tid][c] - m);
        lr[tid] = m + __logf(s);
    } else {
        int c = tid - BS;
        float m = -1e30f;
        for (int r = 0; r < BS; ++r) m = fmaxf(m, S[r][c]);
        float s = 0.f;
        for (int r = 0; r < BS; ++r) s += __expf(S[r][c] - m);
        lc[c] = m + __logf(s);
    }
    __syncthreads();
    if (tid == 0) {
        float a = 0.f;
        for (int i = 0; i < BS; ++i) a += S[i][i] - 0.5f * lr[i] - 0.5f * lc[i];
        out[0] = -a / (float)BS;
    }
}

extern "C" void kernel_launch(void* const* d_in, const int* in_sizes, int n_in,
                              void* d_out, int out_size, void* d_ws, size_t ws_size,
                              hipStream_t stream)
{
    const float* traj = (const float*)d_in[0];
    const float* ff   = (const float*)d_in[1];
    const float* sent = (const float*)d_in[2];
    const float* wf   = (const float*)d_in[3];
    const float* G    = (const float*)d_in[4];
    const float* Wl   = (const float*)d_in[5];
    const float* Fl   = (const float*)d_in[6];
    const float* L    = (const float*)d_in[7];
    const float* Fm   = (const float*)d_in[8];
    const float* Wm   = (const float*)d_in[9];
    const float* F2   = (const float*)d_in[10];
    const float* Wm2  = (const float*)d_in[11];
    float* out = (float*)d_out;
    char* base = (char*)d_ws;

    // ws layout (bytes)
    float* sg     = (float*)(base);                 // 393216
    float* sim    = (float*)(base + 393216);        // 65536
    u16*   wl_hi  = (u16*)(base + 458752);          // 15728640
    u16*   wl_lo  = (u16*)(base + 16187392);        // 15728640
    u16*   ff_hi  = (u16*)(base + 31916032);        // 12582912
    u16*   ff_lo  = (u16*)(base + 44498944);        // 12582912
    u16*   WmT_hi = (u16*)(base + 57081856);        // 15360
    u16*   WmT_lo = (u16*)(base + 57097216);        // 15360
    u16*   FmT_hi = (u16*)(base + 57112576);        // 8192
    u16*   FmT_lo = (u16*)(base + 57120768);        // 8192 -> 57128960 total

    hipLaunchKernelGGL(k_sent_global, dim3(BS * DD / 256), dim3(256), 0, stream, sent, G, sg);
    hipLaunchKernelGGL(k_traj_sent, dim3(8, 8), dim3(256), 0, stream, sg, traj, sim);
    hipLaunchKernelGGL(k_prepw, dim3(46), dim3(256), 0, stream, Wm, Fm, WmT_hi, WmT_lo, FmT_hi, FmT_lo);
    hipLaunchKernelGGL(k_ffsplit, dim3(BS * NF * DD / 1024), dim3(256), 0, stream, ff, ff_hi, ff_lo);
    hipLaunchKernelGGL(k_wl, dim3(6, 80), dim3(256), 0, stream, wf, L, wl_hi, wl_lo);
    hipLaunchKernelGGL(k_video_word, dim3(2, BS), dim3(256), 0, stream, wf, traj, Wl, sim);
    hipLaunchKernelGGL(k_sent_frame, dim3(2, BS), dim3(256), 0, stream, sent, ff, Fl, sim);
    hipLaunchKernelGGL(k_frame_word, dim3(BS, BS), dim3(256), 0, stream,
                       wl_hi, wl_lo, ff_hi, ff_lo, WmT_hi, WmT_lo, FmT_hi, FmT_lo, F2, Wm2, sim);
    hipLaunchKernelGGL(k_loss, dim3(1), dim3(256), 0, stream, sim, out);
}

// Round 4
// 1483.083 us; speedup vs baseline: 3.9205x; 1.0339x over previous
//
#include <hip/hip_runtime.h>
#include <math.h>

#define BS 128
#define NW 80
#define NF 64
#define DD 768
#define INV_TAU 100.0f

typedef unsigned short u16;
typedef unsigned int u32;
typedef __attribute__((ext_vector_type(8))) short bf16x8;
typedef __attribute__((ext_vector_type(4))) float f32x4;

__device__ __forceinline__ u16 f2bf(float x) {
    unsigned b = __float_as_uint(x);
    return (u16)((b + 0x7fffu + ((b >> 16) & 1u)) >> 16);
}
__device__ __forceinline__ float bf2f(u16 h) { return __uint_as_float(((unsigned)h) << 16); }

__device__ __forceinline__ void gload_lds16(const void* gsrc, void* ldst) {
    __builtin_amdgcn_global_load_lds(
        (const __attribute__((address_space(1))) unsigned int*)gsrc,
        (__attribute__((address_space(3))) unsigned int*)ldst, 16, 0, 0);
}

// ---------------- K1: sg = sentence_output @ global_mat_weight ----------------
__global__ __launch_bounds__(256) void k_sent_global(
    const float* __restrict__ sent, const float* __restrict__ G, float* __restrict__ sg)
{
    int idx = blockIdx.x * 256 + threadIdx.x;
    int t = idx / DD, e = idx % DD;
    const float* srow = sent + t * DD;
    float acc = 0.f;
    #pragma unroll 4
    for (int d = 0; d < DD; ++d) acc += srow[d] * G[d * DD + e];
    sg[idx] = acc;
}

// ---------------- K1b: sim = 0.25 * sg @ traj^T (first writer of sim) ----------------
__global__ __launch_bounds__(256) void k_traj_sent(
    const float* __restrict__ sg, const float* __restrict__ traj, float* __restrict__ sim)
{
    __shared__ float ss[16][33], tt[16][33];
    int tx = threadIdx.x & 15, ty = threadIdx.x >> 4;
    int t0 = blockIdx.y * 16, v0 = blockIdx.x * 16;
    float acc = 0.f;
    for (int kk = 0; kk < DD; kk += 32) {
        for (int l = threadIdx.x; l < 16 * 32; l += 256) {
            int r = l >> 5, c = l & 31;
            ss[r][c] = sg[(t0 + r) * DD + kk + c];
            tt[r][c] = traj[(v0 + r) * DD + kk + c];
        }
        __syncthreads();
        #pragma unroll
        for (int k = 0; k < 32; ++k) acc += ss[ty][k] * tt[tx][k];
        __syncthreads();
    }
    sim[(t0 + ty) * BS + v0 + tx] = 0.25f * acc;
}

// ---------------- K_prepw: WmT[80][96] hi/lo (zero-padded), FmT[64][64] hi/lo ----------------
__global__ __launch_bounds__(256) void k_prepw(
    const float* __restrict__ Wm, const float* __restrict__ Fm,
    u16* __restrict__ WmT_hi, u16* __restrict__ WmT_lo,
    u16* __restrict__ FmT_hi, u16* __restrict__ FmT_lo)
{
    int gid = blockIdx.x * 256 + threadIdx.x;
    if (gid < 80 * 96) {
        int u = gid / 96, w = gid % 96;
        float x = (w < 80) ? Wm[w * 80 + u] : 0.f;
        u16 h = f2bf(x);
        WmT_hi[gid] = h; WmT_lo[gid] = f2bf(x - bf2f(h));
    } else if (gid < 80 * 96 + 64 * 64) {
        int j = gid - 80 * 96;
        int fp = j >> 6, f = j & 63;
        float x = Fm[f * 64 + fp];
        u16 h = f2bf(x);
        FmT_hi[j] = h; FmT_lo[j] = f2bf(x - bf2f(h));
    }
}

// ---------------- K2b: split ff to bf16 hi/lo ----------------
__global__ __launch_bounds__(256) void k_ffsplit(
    const float* __restrict__ x, u16* __restrict__ hi, u16* __restrict__ lo)
{
    int i = blockIdx.x * 256 + threadIdx.x;
    float4 f = *(const float4*)&x[(size_t)i * 4];
    ushort4 h, l;
    h.x = f2bf(f.x); l.x = f2bf(f.x - bf2f(h.x));
    h.y = f2bf(f.y); l.y = f2bf(f.y - bf2f(h.y));
    h.z = f2bf(f.z); l.z = f2bf(f.z - bf2f(h.z));
    h.w = f2bf(f.w); l.w = f2bf(f.w - bf2f(h.w));
    *(ushort4*)&hi[(size_t)i * 4] = h;
    *(ushort4*)&lo[(size_t)i * 4] = l;
}

// ---------------- K2: wl = wf @ L via split-bf16 MFMA (reg-staged) ----------------
__global__ __launch_bounds__(256, 2) void k_wl(
    const float* __restrict__ wf, const float* __restrict__ L,
    u16* __restrict__ wl_hi, u16* __restrict__ wl_lo)
{
    __shared__ u16 Ah[128][72], Al[128][72];
    __shared__ u16 Bh[128][72], Bl[128][72];
    const int tid = threadIdx.x;
    const int lane = tid & 63, wid = tid >> 6;
    const int m0 = blockIdx.y * 128, n0 = blockIdx.x * 128;

    f32x4 acc[2][8];
    #pragma unroll
    for (int i = 0; i < 2; ++i)
        #pragma unroll
        for (int j = 0; j < 8; ++j) acc[i][j] = (f32x4){0.f, 0.f, 0.f, 0.f};

    for (int kk = 0; kk < DD; kk += 64) {
        #pragma unroll
        for (int p = 0; p < 8; ++p) {
            int row = p * 16 + (tid >> 4), c4 = tid & 15;
            float4 v = *(const float4*)&wf[(size_t)(m0 + row) * DD + kk + c4 * 4];
            ushort4 h, l;
            h.x = f2bf(v.x); l.x = f2bf(v.x - bf2f(h.x));
            h.y = f2bf(v.y); l.y = f2bf(v.y - bf2f(h.y));
            h.z = f2bf(v.z); l.z = f2bf(v.z - bf2f(h.z));
            h.w = f2bf(v.w); l.w = f2bf(v.w - bf2f(h.w));
            *(ushort4*)&Ah[row][c4 * 4] = h;
            *(ushort4*)&Al[row][c4 * 4] = l;
        }
        #pragma unroll
        for (int p = 0; p < 8; ++p) {
            int kr = p * 8 + (tid >> 5), c4 = tid & 31;
            float4 v = *(const float4*)&L[(size_t)(kk + kr) * DD + n0 + c4 * 4];
            #pragma unroll
            for (int jj = 0; jj < 4; ++jj) {
                int n = c4 * 4 + jj;
                float x = (jj == 0) ? v.x : (jj == 1) ? v.y : (jj == 2) ? v.z : v.w;
                u16 h = f2bf(x);
                int ka = kr ^ ((n & 7) << 3);
                Bh[n][ka] = h;
                Bl[n][ka] = f2bf(x - bf2f(h));
            }
        }
        __syncthreads();
        #pragma unroll
        for (int ks = 0; ks < 2; ++ks) {
            int koff = ks * 32 + (lane >> 4) * 8;
            bf16x8 ah[2], al[2];
            #pragma unroll
            for (int i = 0; i < 2; ++i) {
                int row = wid * 32 + 16 * i + (lane & 15);
                ah[i] = *(const bf16x8*)&Ah[row][koff];
                al[i] = *(const bf16x8*)&Al[row][koff];
            }
            #pragma unroll
            for (int j = 0; j < 8; ++j) {
                int n = 16 * j + (lane & 15);
                int kb = koff ^ ((n & 7) << 3);
                bf16x8 bh = *(const bf16x8*)&Bh[n][kb];
                bf16x8 bl = *(const bf16x8*)&Bl[n][kb];
                #pragma unroll
                for (int i = 0; i < 2; ++i) {
                    acc[i][j] = __builtin_amdgcn_mfma_f32_16x16x32_bf16(ah[i], bh, acc[i][j], 0, 0, 0);
                    acc[i][j] = __builtin_amdgcn_mfma_f32_16x16x32_bf16(ah[i], bl, acc[i][j], 0, 0, 0);
                    acc[i][j] = __builtin_amdgcn_mfma_f32_16x16x32_bf16(al[i], bh, acc[i][j], 0, 0, 0);
                }
            }
        }
        __syncthreads();
    }
    #pragma unroll
    for (int i = 0; i < 2; ++i)
        #pragma unroll
        for (int j = 0; j < 8; ++j)
            #pragma unroll
            for (int r = 0; r < 4; ++r) {
                float x = acc[i][j][r];
                int row = m0 + wid * 32 + 16 * i + ((lane >> 4) << 2) + r;
                int col = n0 + 16 * j + (lane & 15);
                size_t idx = (size_t)row * DD + col;
                u16 h = f2bf(x);
                wl_hi[idx] = h;
                wl_lo[idx] = f2bf(x - bf2f(h));
            }
}

// ---------------- K3: video_word (fp32, unchanged) ----------------
__global__ __launch_bounds__(256, 2) void k_video_word(
    const float* __restrict__ wf, const float* __restrict__ traj,
    const float* __restrict__ Wl, float* __restrict__ sim)
{
    __shared__ __align__(16) float As[NW][36];
    __shared__ __align__(16) float Bs[64][36];
    __shared__ float Am[NW][65];
    __shared__ float Pm[NW][65];
    int tx = threadIdx.x & 15, ty = threadIdx.x >> 4;
    int t = blockIdx.y, v0 = blockIdx.x * 64;
    const float* wft = wf + t * NW * DD;
    float acc[5][4] = {};
    for (int kk = 0; kk < DD; kk += 32) {
        for (int l = threadIdx.x; l < NW * 32; l += 256) {
            int w = l >> 5, k = l & 31;
            As[w][k] = wft[w * DD + kk + k];
        }
        for (int l = threadIdx.x; l < 64 * 32; l += 256) {
            int v = l >> 5, k = l & 31;
            Bs[v][k] = traj[(v0 + v) * DD + kk + k];
        }
        __syncthreads();
        #pragma unroll
        for (int k = 0; k < 32; k += 4) {
            float4 a[5], b[4];
            #pragma unroll
            for (int i = 0; i < 5; ++i) a[i] = *(const float4*)&As[tx + 16 * i][k];
            #pragma unroll
            for (int j = 0; j < 4; ++j) b[j] = *(const float4*)&Bs[ty + 16 * j][k];
            #pragma unroll
            for (int i = 0; i < 5; ++i)
                #pragma unroll
                for (int j = 0; j < 4; ++j)
                    acc[i][j] += a[i].x * b[j].x + a[i].y * b[j].y + a[i].z * b[j].z + a[i].w * b[j].w;
        }
        __syncthreads();
    }
    #pragma unroll
    for (int i = 0; i < 5; ++i)
        #pragma unroll
        for (int j = 0; j < 4; ++j) Am[tx + 16 * i][ty + 16 * j] = acc[i][j];
    __syncthreads();
    if (threadIdx.x < 64) {
        int v = threadIdx.x;
        float m = -1e30f;
        for (int w = 0; w < NW; ++w) m = fmaxf(m, Am[w][v]);
        float s = 0.f;
        for (int w = 0; w < NW; ++w) { float e = __expf((Am[w][v] - m) * INV_TAU); Pm[w][v] = e; s += e; }
        float r = 1.f / s;
        for (int w = 0; w < NW; ++w) Pm[w][v] *= r;
    }
    __syncthreads();
    float mm[5][4] = {};
    for (int w = 0; w < NW; ++w) {
        float a[5], b[4];
        #pragma unroll
        for (int i = 0; i < 5; ++i) a[i] = Wl[w * NW + tx + 16 * i];
        #pragma unroll
        for (int j = 0; j < 4; ++j) b[j] = Pm[w][ty + 16 * j];
        #pragma unroll
        for (int i = 0; i < 5; ++i)
            #pragma unroll
            for (int j = 0; j < 4; ++j) mm[i][j] += a[i] * b[j];
    }
    #pragma unroll
    for (int j = 0; j < 4; ++j) {
        float p = 0.f;
        #pragma unroll
        for (int i = 0; i < 5; ++i) p += mm[i][j] * Am[tx + 16 * i][ty + 16 * j];
        for (int o = 8; o; o >>= 1) p += __shfl_xor(p, o, 16);
        if (tx == 0) sim[t * BS + v0 + ty + 16 * j] += 0.25f * p;
    }
}

// ---------------- K4: sentence_frame (fp32, unchanged) ----------------
__global__ __launch_bounds__(256, 2) void k_sent_frame(
    const float* __restrict__ sent, const float* __restrict__ ff,
    const float* __restrict__ Fl, float* __restrict__ sim)
{
    __shared__ __align__(16) float Ss[64][36];
    __shared__ __align__(16) float Fs[64][36];
    __shared__ float Bm[64][65];
    __shared__ float Pm[64][65];
    int tx = threadIdx.x & 15, ty = threadIdx.x >> 4;
    int v = blockIdx.y, t0 = blockIdx.x * 64;
    const float* ffv = ff + v * NF * DD;
    float acc[4][4] = {};
    for (int kk = 0; kk < DD; kk += 32) {
        for (int l = threadIdx.x; l < 64 * 32; l += 256) {
            int r = l >> 5, k = l & 31;
            Ss[r][k] = sent[(t0 + r) * DD + kk + k];
            Fs[r][k] = ffv[r * DD + kk + k];
        }
        __syncthreads();
        #pragma unroll
        for (int k = 0; k < 32; k += 4) {
            float4 a[4], b[4];
            #pragma unroll
            for (int i = 0; i < 4; ++i) a[i] = *(const float4*)&Ss[tx + 16 * i][k];
            #pragma unroll
            for (int j = 0; j < 4; ++j) b[j] = *(const float4*)&Fs[ty + 16 * j][k];
            #pragma unroll
            for (int i = 0; i < 4; ++i)
                #pragma unroll
                for (int j = 0; j < 4; ++j)
                    acc[i][j] += a[i].x * b[j].x + a[i].y * b[j].y + a[i].z * b[j].z + a[i].w * b[j].w;
        }
        __syncthreads();
    }
    #pragma unroll
    for (int i = 0; i < 4; ++i)
        #pragma unroll
        for (int j = 0; j < 4; ++j) Bm[tx + 16 * i][ty + 16 * j] = acc[i][j];
    __syncthreads();
    if (threadIdx.x < 64) {
        int r = threadIdx.x;
        float m = -1e30f;
        for (int f = 0; f < NF; ++f) m = fmaxf(m, Bm[r][f]);
        float s = 0.f;
        for (int f = 0; f < NF; ++f) { float e = __expf((Bm[r][f] - m) * INV_TAU); Pm[r][f] = e; s += e; }
        float rr = 1.f / s;
        for (int f = 0; f < NF; ++f) Pm[r][f] *= rr;
    }
    __syncthreads();
    float nn[4][4] = {};
    for (int f = 0; f < NF; ++f) {
        float a[4], b[4];
        #pragma unroll
        for (int i = 0; i < 4; ++i) a[i] = Pm[ty + 16 * i][f];
        #pragma unroll
        for (int j = 0; j < 4; ++j) b[j] = Fl[f * NF + tx + 16 * j];
        #pragma unroll
        for (int i = 0; i < 4; ++i)
            #pragma unroll
            for (int j = 0; j < 4; ++j) nn[i][j] += a[i] * b[j];
    }
    #pragma unroll
    for (int i = 0; i < 4; ++i) {
        float p = 0.f;
        #pragma unroll
        for (int j = 0; j < 4; ++j) p += nn[i][j] * Bm[ty + 16 * i][tx + 16 * j];
        for (int o = 8; o; o >>= 1) p += __shfl_xor(p, o, 16);
        if (tx == 0) sim[(t0 + ty + 16 * i) * BS + v] += 0.25f * p;
    }
}

// ---------------- K5: frame_word — MFMA S-GEMM + on-the-fly MFMA mixes ----------------
__global__ __launch_bounds__(256, 4) void k_frame_word(
    const u16* __restrict__ wl_hi, const u16* __restrict__ wl_lo,
    const u16* __restrict__ ff_hi, const u16* __restrict__ ff_lo,
    const u16* __restrict__ WmT_hi, const u16* __restrict__ WmT_lo,
    const u16* __restrict__ FmT_hi, const u16* __restrict__ FmT_lo,
    const float* __restrict__ F2, const float* __restrict__ Wm2,
    float* __restrict__ sim)
{
    __shared__ __align__(16) union SH {
        u16 stage[18432];                       // 36864 B (GEMM phase)
        struct Post {
            float Sm[80][65];                   // 20800
            float redm[4][64], reds[4][64];     // 2048
            float colM[64], colRD[64];          // 512
            float rowM[80], rowRD[80];          // 640
            float wlv[64], flv[80], flvp[4][80];// 1856
            float smw[64], smf[80];             // 576
            float s2f, v2w;
        } post;                                 // ~26.5 KB
    } sh;

    const int tid = threadIdx.x;
    const int lane = tid & 63, wid = tid >> 6;
    const int col = lane & 15, grp = lane >> 4;
    const int v = blockIdx.x, t = blockIdx.y;

    f32x4 acc[5], acc2[5];
    #pragma unroll
    for (int i = 0; i < 5; ++i) { acc[i] = (f32x4){0.f,0.f,0.f,0.f}; acc2[i] = (f32x4){0.f,0.f,0.f,0.f}; }

    const int r8 = lane >> 3, s8 = lane & 7;
    const int gk = s8 ^ r8;

    // ---- S-GEMM: S = wl_t[80x768] @ ff_v[64x768]^T, split-bf16 3-pass ----
    for (int kk = 0; kk < DD; kk += 64) {
        for (int seg = wid; seg < 36; seg += 4) {
            const u16* src;
            int ldsoff;
            if (seg < 10) {
                int g = seg, row = g * 8 + r8;
                src = wl_hi + (size_t)(t * NW + row) * DD + kk + gk * 8;
                ldsoff = g * 512;
            } else if (seg < 20) {
                int g = seg - 10, row = g * 8 + r8;
                src = wl_lo + (size_t)(t * NW + row) * DD + kk + gk * 8;
                ldsoff = 5120 + g * 512;
            } else if (seg < 28) {
                int g = seg - 20, row = g * 8 + r8;
                src = ff_hi + (size_t)(v * NF + row) * DD + kk + gk * 8;
                ldsoff = 10240 + g * 512;
            } else {
                int g = seg - 28, row = g * 8 + r8;
                src = ff_lo + (size_t)(v * NF + row) * DD + kk + gk * 8;
                ldsoff = 14336 + g * 512;
            }
            gload_lds16(src, (void*)&sh.stage[ldsoff]);
        }
        __syncthreads();
        const u16* st = sh.stage;
        #pragma unroll
        for (int ks = 0; ks < 2; ++ks) {
            const int sl = (ks << 2) + grp;
            bf16x8 afh[5], afl[5], bfh, bfl;
            #pragma unroll
            for (int i = 0; i < 5; ++i) {
                int row = col + 16 * i;
                int off = row * 64 + ((sl ^ (row & 7)) << 3);
                afh[i] = *(const bf16x8*)&st[off];
                afl[i] = *(const bf16x8*)&st[5120 + off];
            }
            {
                int row = col + 16 * wid;
                int off = row * 64 + ((sl ^ (row & 7)) << 3);
                bfh = *(const bf16x8*)&st[10240 + off];
                bfl = *(const bf16x8*)&st[14336 + off];
            }
            // pass-major, two independent accumulator sets -> 10 indep chains
            #pragma unroll
            for (int i = 0; i < 5; ++i)
                acc[i] = __builtin_amdgcn_mfma_f32_16x16x32_bf16(afh[i], bfh, acc[i], 0, 0, 0);
            #pragma unroll
            for (int i = 0; i < 5; ++i)
                acc2[i] = __builtin_amdgcn_mfma_f32_16x16x32_bf16(afh[i], bfl, acc2[i], 0, 0, 0);
            #pragma unroll
            for (int i = 0; i < 5; ++i)
                acc[i] = __builtin_amdgcn_mfma_f32_16x16x32_bf16(afl[i], bfh, acc[i], 0, 0, 0);
        }
        __syncthreads();
    }

    // ---- write S to LDS (stage region dead) ----
    #pragma unroll
    for (int i = 0; i < 5; ++i)
        #pragma unroll
        for (int r = 0; r < 4; ++r)
            sh.post.Sm[16 * i + (grp << 2) + r][col + (wid << 4)] = acc[i][r] + acc2[i][r];
    __syncthreads();

    // ---- column softmax stats (per f): colM, colRD = 1/sum ----
    {
        const int f = tid & 63, q = tid >> 6, w0 = q * 20;
        float m = -1e30f;
        for (int w = w0; w < w0 + 20; ++w) m = fmaxf(m, sh.post.Sm[w][f]);
        float s = 0.f;
        for (int w = w0; w < w0 + 20; ++w) s += __expf((sh.post.Sm[w][f] - m) * INV_TAU);
        sh.post.redm[q][f] = m; sh.post.reds[q][f] = s;
        __syncthreads();
        if (q == 0) {
            float M = -1e30f;
            #pragma unroll
            for (int qq = 0; qq < 4; ++qq) M = fmaxf(M, sh.post.redm[qq][f]);
            float Dn = 0.f;
            #pragma unroll
            for (int qq = 0; qq < 4; ++qq) Dn += sh.post.reds[qq][f] * __expf((sh.post.redm[qq][f] - M) * INV_TAU);
            sh.post.colM[f] = M;
            sh.post.colRD[f] = 1.f / Dn;
        }
    }
    __syncthreads();

    // ---- mix1 (MFMA, B on-the-fly): D1[u][f] = sum_w WmT[u][w]*P[w][f]; wlv[f] = sum_u D1*S ----
    {
        f32x4 d1[5], d1b[5];
        #pragma unroll
        for (int i = 0; i < 5; ++i) { d1[i] = (f32x4){0.f,0.f,0.f,0.f}; d1b[i] = (f32x4){0.f,0.f,0.f,0.f}; }
        const int f = wid * 16 + col;
        const float Mf = sh.post.colM[f], RDf = sh.post.colRD[f];
        #pragma unroll
        for (int ks = 0; ks < 3; ++ks) {
            const int w0 = ks * 32 + grp * 8;
            union { u16 h[8]; bf16x8 v; } bh, bl;
            #pragma unroll
            for (int j = 0; j < 8; ++j) {
                int w = w0 + j;
                int wc = (w < NW) ? w : 0;
                float e = __expf((sh.post.Sm[wc][f] - Mf) * INV_TAU) * RDf;
                e = (w < NW) ? e : 0.f;
                u16 hh = f2bf(e);
                bh.h[j] = hh;
                bl.h[j] = f2bf(e - bf2f(hh));
            }
            #pragma unroll
            for (int i = 0; i < 5; ++i) {
                int aaddr = (16 * i + col) * 96 + ks * 32 + grp * 8;
                bf16x8 ah = *(const bf16x8*)&WmT_hi[aaddr];
                bf16x8 al = *(const bf16x8*)&WmT_lo[aaddr];
                d1[i]  = __builtin_amdgcn_mfma_f32_16x16x32_bf16(ah, bh.v, d1[i], 0, 0, 0);
                d1b[i] = __builtin_amdgcn_mfma_f32_16x16x32_bf16(ah, bl.v, d1b[i], 0, 0, 0);
                d1[i]  = __builtin_amdgcn_mfma_f32_16x16x32_bf16(al, bh.v, d1[i], 0, 0, 0);
            }
        }
        float p = 0.f;
        #pragma unroll
        for (int i = 0; i < 5; ++i)
            #pragma unroll
            for (int r = 0; r < 4; ++r)
                p += (d1[i][r] + d1b[i][r]) * sh.post.Sm[16 * i + (grp << 2) + r][f];
        p += __shfl_xor(p, 16);
        p += __shfl_xor(p, 32);
        if (lane < 16) sh.post.wlv[wid * 16 + lane] = p;
    }
    __syncthreads();

    // ---- row softmax stats (per w): rowM, rowRD = 1/sum ----
    if (tid < 160) {
        const int w = tid >> 1, h = tid & 1, f0 = h * 32;
        float m = -1e30f;
        for (int c = 0; c < 32; ++c) m = fmaxf(m, sh.post.Sm[w][f0 + c]);
        m = fmaxf(m, __shfl_xor(m, 1));
        float s = 0.f;
        for (int c = 0; c < 32; ++c) s += __expf((sh.post.Sm[w][f0 + c] - m) * INV_TAU);
        s += __shfl_xor(s, 1);
        if (h == 0) { sh.post.rowM[w] = m; sh.post.rowRD[w] = 1.f / s; }
    }
    __syncthreads();

    // ---- mix2 (MFMA, A on-the-fly): D2[w][f'] = sum_f P2[w][f]*FmT[f'][f]; flv[w] = sum_f' D2*S ----
    {
        f32x4 d2[5], d2b[5];
        #pragma unroll
        for (int i = 0; i < 5; ++i) { d2[i] = (f32x4){0.f,0.f,0.f,0.f}; d2b[i] = (f32x4){0.f,0.f,0.f,0.f}; }
        #pragma unroll
        for (int ks = 0; ks < 2; ++ks) {
            int baddr = (wid * 16 + col) * 64 + ks * 32 + grp * 8;
            bf16x8 bh = *(const bf16x8*)&FmT_hi[baddr];
            bf16x8 bl = *(const bf16x8*)&FmT_lo[baddr];
            #pragma unroll
            for (int i = 0; i < 5; ++i) {
                const int row = 16 * i + col;
                const float Mw = sh.post.rowM[row], RDw = sh.post.rowRD[row];
                const int f0 = ks * 32 + grp * 8;
                union { u16 h[8]; bf16x8 v; } ah, al;
                #pragma unroll
                for (int j = 0; j < 8; ++j) {
                    float e = __expf((sh.post.Sm[row][f0 + j] - Mw) * INV_TAU) * RDw;
                    u16 hh = f2bf(e);
                    ah.h[j] = hh;
                    al.h[j] = f2bf(e - bf2f(hh));
                }
                d2[i]  = __builtin_amdgcn_mfma_f32_16x16x32_bf16(ah.v, bh, d2[i], 0, 0, 0);
                d2b[i] = __builtin_amdgcn_mfma_f32_16x16x32_bf16(ah.v, bl, d2b[i], 0, 0, 0);
                d2[i]  = __builtin_amdgcn_mfma_f32_16x16x32_bf16(al.v, bh, d2[i], 0, 0, 0);
            }
        }
        #pragma unroll
        for (int i = 0; i < 5; ++i)
            #pragma unroll
            for (int r = 0; r < 4; ++r) {
                int w = 16 * i + (grp << 2) + r;
                float p = (d2[i][r] + d2b[i][r]) * sh.post.Sm[w][wid * 16 + col];
                p += __shfl_xor(p, 1);
                p += __shfl_xor(p, 2);
                p += __shfl_xor(p, 4);
                p += __shfl_xor(p, 8);
                if (col == 0) sh.post.flvp[wid][w] = p;
            }
    }
    __syncthreads();
    if (tid < 80)
        sh.post.flv[tid] = sh.post.flvp[0][tid] + sh.post.flvp[1][tid]
                         + sh.post.flvp[2][tid] + sh.post.flvp[3][tid];
    __syncthreads();

    // ---- final softmaxes (wave-parallel) ----
    if (wid == 0) {
        float x = sh.post.wlv[lane];
        float m = x;
        #pragma unroll
        for (int o = 32; o; o >>= 1) m = fmaxf(m, __shfl_xor(m, o));
        float e = __expf((x - m) * INV_TAU);
        float s = e;
        #pragma unroll
        for (int o = 32; o; o >>= 1) s += __shfl_xor(s, o);
        sh.post.smw[lane] = e / s;
    } else if (wid == 1) {
        float x0 = sh.post.flv[lane];
        float x1 = (lane < 16) ? sh.post.flv[64 + lane] : -1e30f;
        float m = fmaxf(x0, x1);
        #pragma unroll
        for (int o = 32; o; o >>= 1) m = fmaxf(m, __shfl_xor(m, o));
        float e0 = __expf((x0 - m) * INV_TAU);
        float e1 = (lane < 16) ? __expf((x1 - m) * INV_TAU) : 0.f;
        float s = e0 + e1;
        #pragma unroll
        for (int o = 32; o; o >>= 1) s += __shfl_xor(s, o);
        sh.post.smf[lane] = e0 / s;
        if (lane < 16) sh.post.smf[64 + lane] = e1 / s;
    }
    __syncthreads();

    if (wid == 0) {                 // sent2frame
        float g = 0.f;
        for (int f = 0; f < NF; ++f) g += sh.post.smw[f] * F2[f * NF + lane];
        float p = g * sh.post.wlv[lane];
        #pragma unroll
        for (int o = 32; o; o >>= 1) p += __shfl_xor(p, o);
        if (lane == 0) sh.post.s2f = p;
    } else if (wid == 1) {          // video2word
        float g = 0.f;
        for (int w = 0; w < NW; ++w) g += sh.post.smf[w] * Wm2[w * NW + lane];
        float p = g * sh.post.flv[lane];
        if (lane < 16) {
            float g2 = 0.f;
            for (int w = 0; w < NW; ++w) g2 += sh.post.smf[w] * Wm2[w * NW + 64 + lane];
            p += g2 * sh.post.flv[64 + lane];
        }
        #pragma unroll
        for (int o = 32; o; o >>= 1) p += __shfl_xor(p, o);
        if (lane == 0) sh.post.v2w = p;
    }
    __syncthreads();
    if (tid == 0) sim[t * BS + v] += 0.125f * (sh.post.s2f + sh.post.v2w);
}

// ---------------- K6: loss from sim ----------------
__global__ __launch_bounds__(256) void k_loss(const float* __restrict__ sim, float* __restrict__ out)
{
    __shared__ float S[BS][BS + 1];
    __shared__ float lr[BS], lc[BS];
    for (int l = threadIdx.x; l < BS * BS; l += 256) {
        int r = l >> 7, c = l & 127;
        S[r][c] = sim[l];
    }
    __syncthreads();
    int tid = threadIdx.x;
    if (tid < BS) {
        float m = -1e30f;
        for (int c = 0; c < BS; ++c) m = fmaxf(m, S[tid][c]);
        float s = 0.f;
        for (int c = 0; c < BS; ++c) s += __expf(S[tid][c] - m);
        lr[tid] = m + __logf(s);
    } else {
        int c = tid - BS;
        float m = -1e30f;
        for (int r = 0; r < BS; ++r) m = fmaxf(m, S[r][c]);
        float s = 0.f;
        for (int r = 0; r < BS; ++r) s += __expf(S[r][c] - m);
        lc[c] = m + __logf(s);
    }
    __syncthreads();
    if (tid == 0) {
        float a = 0.f;
        for (int i = 0; i < BS; ++i) a += S[i][i] - 0.5f * lr[i] - 0.5f * lc[i];
        out[0] = -a / (float)BS;
    }
}

extern "C" void kernel_launch(void* const* d_in, const int* in_sizes, int n_in,
                              void* d_out, int out_size, void* d_ws, size_t ws_size,
                              hipStream_t stream)
{
    const float* traj = (const float*)d_in[0];
    const float* ff   = (const float*)d_in[1];
    const float* sent = (const float*)d_in[2];
    const float* wf   = (const float*)d_in[3];
    const float* G    = (const float*)d_in[4];
    const float* Wl   = (const float*)d_in[5];
    const float* Fl   = (const float*)d_in[6];
    const float* L    = (const float*)d_in[7];
    const float* Fm   = (const float*)d_in[8];
    const float* Wm   = (const float*)d_in[9];
    const float* F2   = (const float*)d_in[10];
    const float* Wm2  = (const float*)d_in[11];
    float* out = (float*)d_out;
    char* base = (char*)d_ws;

    // ws layout (bytes)
    float* sg     = (float*)(base);                 // 393216
    float* sim    = (float*)(base + 393216);        // 65536
    u16*   wl_hi  = (u16*)(base + 458752);          // 15728640
    u16*   wl_lo  = (u16*)(base + 16187392);        // 15728640
    u16*   ff_hi  = (u16*)(base + 31916032);        // 12582912
    u16*   ff_lo  = (u16*)(base + 44498944);        // 12582912
    u16*   WmT_hi = (u16*)(base + 57081856);        // 15360
    u16*   WmT_lo = (u16*)(base + 57097216);        // 15360
    u16*   FmT_hi = (u16*)(base + 57112576);        // 8192
    u16*   FmT_lo = (u16*)(base + 57120768);        // 8192 -> 57128960 total

    hipLaunchKernelGGL(k_sent_global, dim3(BS * DD / 256), dim3(256), 0, stream, sent, G, sg);
    hipLaunchKernelGGL(k_traj_sent, dim3(8, 8), dim3(256), 0, stream, sg, traj, sim);
    hipLaunchKernelGGL(k_prepw, dim3(46), dim3(256), 0, stream, Wm, Fm, WmT_hi, WmT_lo, FmT_hi, FmT_lo);
    hipLaunchKernelGGL(k_ffsplit, dim3(BS * NF * DD / 1024), dim3(256), 0, stream, ff, ff_hi, ff_lo);
    hipLaunchKernelGGL(k_wl, dim3(6, 80), dim3(256), 0, stream, wf, L, wl_hi, wl_lo);
    hipLaunchKernelGGL(k_video_word, dim3(2, BS), dim3(256), 0, stream, wf, traj, Wl, sim);
    hipLaunchKernelGGL(k_sent_frame, dim3(2, BS), dim3(256), 0, stream, sent, ff, Fl, sim);
    hipLaunchKernelGGL(k_frame_word, dim3(BS, BS), dim3(256), 0, stream,
                       wl_hi, wl_lo, ff_hi, ff_lo, WmT_hi, WmT_lo, FmT_hi, FmT_lo, F2, Wm2, sim);
    hipLaunchKernelGGL(k_loss, dim3(1), dim3(256), 0, stream, sim, out);
}